// Round 1
// baseline (4980.846 us; speedup 1.0000x reference)
//
#include <hip/hip_runtime.h>
#include <math.h>

#define B_ 8
#define N_ 1023
#define S_ 1024
#define E_ 256
#define H_ 8
#define D_ 32
#define L_ 6
#define F_ 1024

// ---------------------------------------------------------------------------
// dist bias: bias[b,q,k] = table[min(d,31)] (d==-1 -> idx 32 -> JAX clamps to 31)
__global__ __launch_bounds__(256) void bias_kernel(const int* __restrict__ dm,
                                                   const float* __restrict__ table,
                                                   float* __restrict__ out) {
    int idx = blockIdx.x * 256 + threadIdx.x;          // exactly B_*S_*S_
    int d = dm[idx];
    int ii = ((unsigned)d > 30u) ? 31 : d;
    out[idx] = table[ii];
}

// op embedding gather into left half of hcat (ld 512)
__global__ __launch_bounds__(256) void opgather_kernel(const int* __restrict__ opc,
                                                       const float* __restrict__ W_op,
                                                       float* __restrict__ hcat) {
    int idx = blockIdx.x * 256 + threadIdx.x;          // 8184*256
    int row = idx >> 8, c = idx & 255;
    hcat[(size_t)row * 512 + c] = W_op[opc[row] * 256 + c];
}

// x[b,0,:]=cls ; x[b,1+n,:]=h[b*N+n,:]
__global__ __launch_bounds__(256) void assemble_kernel(const float* __restrict__ cls,
                                                       const float* __restrict__ h,
                                                       float* __restrict__ x) {
    int idx = blockIdx.x * 256 + threadIdx.x;          // B_*S_*E_
    int c = idx & 255;
    int s = (idx >> 8) & 1023;
    int b = idx >> 18;
    x[idx] = (s == 0) ? cls[c] : h[((size_t)(b * N_ + s - 1)) * 256 + c];
}

// ---------------------------------------------------------------------------
// Guarded tiled fp32 GEMM: C[M,N] = epi(A[M,K] @ B[K,N] + bias[N])
// BM=BN=64, BK=16, 256 threads, 4x4 per-thread tile, float4 LDS fragments.
// EPI: 0 = none, 1 = exact GELU.
template<int EPI>
__global__ __launch_bounds__(256) void gemm_kernel(
    const float* __restrict__ A, int lda,
    const float* __restrict__ Bm, int ldb,
    const float* __restrict__ bias,
    float* __restrict__ C, int ldc,
    int M, int N, int K)
{
    __shared__ float As[16][68];   // transposed: As[k][m]
    __shared__ float Bs[16][68];   // Bs[k][n]
    const int t = threadIdx.x;
    const int m0 = blockIdx.x * 64, n0 = blockIdx.y * 64;
    const int tx = t & 15, ty = t >> 4;
    const int tm = ty * 4, tn = tx * 4;
    float acc[4][4] = {};
    const int am = t >> 2, ak = (t & 3) * 4;
    const int bkr = t >> 4, bn4 = (t & 15) * 4;
    const int nt = (K + 15) >> 4;
    for (int kt = 0; kt < nt; kt++) {
        int k0 = kt * 16;
        #pragma unroll
        for (int j = 0; j < 4; j++) {
            int kk = k0 + ak + j;
            float v = 0.f;
            if (m0 + am < M && kk < K) v = A[(size_t)(m0 + am) * lda + kk];
            As[ak + j][am] = v;
        }
        {
            float4 v = {0.f, 0.f, 0.f, 0.f};
            if (k0 + bkr < K) v = *(const float4*)&Bm[(size_t)(k0 + bkr) * ldb + n0 + bn4];
            *(float4*)&Bs[bkr][bn4] = v;
        }
        __syncthreads();
        #pragma unroll
        for (int kk = 0; kk < 16; kk++) {
            float4 a = *(const float4*)&As[kk][tm];
            float4 b = *(const float4*)&Bs[kk][tn];
            float av[4] = {a.x, a.y, a.z, a.w};
            float bw[4] = {b.x, b.y, b.z, b.w};
            #pragma unroll
            for (int i = 0; i < 4; i++)
                #pragma unroll
                for (int j = 0; j < 4; j++)
                    acc[i][j] = fmaf(av[i], bw[j], acc[i][j]);
        }
        __syncthreads();
    }
    #pragma unroll
    for (int j = 0; j < 4; j++) {
        float bv = bias ? bias[n0 + tn + j] : 0.f;
        #pragma unroll
        for (int i = 0; i < 4; i++) {
            int m = m0 + tm + i;
            if (m < M) {
                float v = acc[i][j] + bv;
                if (EPI == 1) v = 0.5f * v * (1.f + erff(v * 0.70710678118654752f));
                C[(size_t)m * ldc + n0 + tn + j] = v;
            }
        }
    }
}

// ---------------------------------------------------------------------------
// Flash-style attention. Block = 64 threads (1 wave) = 64 query rows for one
// (b,h). K/V tiles of 32 rows staged in LDS; bias read from precomputed buf;
// online softmax in registers. q pre-scaled by 1/sqrt(D).
__global__ __launch_bounds__(64) void attn_kernel(
    const float* __restrict__ q, const float* __restrict__ k,
    const float* __restrict__ v, const float* __restrict__ bias,
    float* __restrict__ ctx)
{
    __shared__ float Ks[32][36];
    __shared__ float Vs[32][36];
    const int t = threadIdx.x;
    const int bid = blockIdx.x;
    const int qt = bid & 15;
    const int h = (bid >> 4) & 7;
    const int b = bid >> 7;
    const int qrow = qt * 64 + t;
    const float scale = 0.17677669529663687f;

    float4 qr[8];
    const float* qp = q + ((size_t)(b * S_ + qrow)) * E_ + h * D_;
    #pragma unroll
    for (int i = 0; i < 8; i++) {
        float4 tv = *(const float4*)&qp[i * 4];
        qr[i].x = tv.x * scale; qr[i].y = tv.y * scale;
        qr[i].z = tv.z * scale; qr[i].w = tv.w * scale;
    }
    float4 o[8] = {};
    float mrun = -1e30f, lrun = 0.f;
    const float* bp = bias + ((size_t)(b * S_ + qrow)) * S_;
    const int r = t >> 1, c0 = (t & 1) * 16;

    for (int kt = 0; kt < S_; kt += 32) {
        const float* kp = k + ((size_t)(b * S_ + kt + r)) * E_ + h * D_ + c0;
        const float* vp = v + ((size_t)(b * S_ + kt + r)) * E_ + h * D_ + c0;
        #pragma unroll
        for (int i = 0; i < 4; i++) {
            *(float4*)&Ks[r][c0 + i * 4] = *(const float4*)&kp[i * 4];
            *(float4*)&Vs[r][c0 + i * 4] = *(const float4*)&vp[i * 4];
        }
        __syncthreads();

        float s[32];
        #pragma unroll
        for (int k4 = 0; k4 < 8; k4++) {
            float4 bb = *(const float4*)&bp[kt + k4 * 4];
            s[k4 * 4 + 0] = bb.x; s[k4 * 4 + 1] = bb.y;
            s[k4 * 4 + 2] = bb.z; s[k4 * 4 + 3] = bb.w;
        }
        #pragma unroll
        for (int d4 = 0; d4 < 8; d4++) {
            float4 qv = qr[d4];
            #pragma unroll
            for (int kk = 0; kk < 32; kk++) {
                float4 kv = *(const float4*)&Ks[kk][d4 * 4];
                s[kk] = fmaf(qv.x, kv.x, s[kk]);
                s[kk] = fmaf(qv.y, kv.y, s[kk]);
                s[kk] = fmaf(qv.z, kv.z, s[kk]);
                s[kk] = fmaf(qv.w, kv.w, s[kk]);
            }
        }
        float tmax = s[0];
        #pragma unroll
        for (int kk = 1; kk < 32; kk++) tmax = fmaxf(tmax, s[kk]);
        float mnew = fmaxf(mrun, tmax);
        float corr = __expf(mrun - mnew);
        lrun *= corr;
        #pragma unroll
        for (int d4 = 0; d4 < 8; d4++) {
            o[d4].x *= corr; o[d4].y *= corr; o[d4].z *= corr; o[d4].w *= corr;
        }
        float ps = 0.f;
        #pragma unroll
        for (int kk = 0; kk < 32; kk++) { s[kk] = __expf(s[kk] - mnew); ps += s[kk]; }
        lrun += ps;
        #pragma unroll
        for (int kk = 0; kk < 32; kk++) {
            float p = s[kk];
            #pragma unroll
            for (int d4 = 0; d4 < 8; d4++) {
                float4 vv = *(const float4*)&Vs[kk][d4 * 4];
                o[d4].x = fmaf(p, vv.x, o[d4].x);
                o[d4].y = fmaf(p, vv.y, o[d4].y);
                o[d4].z = fmaf(p, vv.z, o[d4].z);
                o[d4].w = fmaf(p, vv.w, o[d4].w);
            }
        }
        mrun = mnew;
        __syncthreads();
    }
    float inv = 1.f / lrun;
    float* op = ctx + ((size_t)(b * S_ + qrow)) * E_ + h * D_;
    #pragma unroll
    for (int d4 = 0; d4 < 8; d4++) {
        float4 ov;
        ov.x = o[d4].x * inv; ov.y = o[d4].y * inv;
        ov.z = o[d4].z * inv; ov.w = o[d4].w * inv;
        *(float4*)&op[d4 * 4] = ov;
    }
}

// ---------------------------------------------------------------------------
// xout = LN(xin + add) * g + b   (one wave per 256-elem row)
__global__ __launch_bounds__(64) void ln_kernel(
    const float* __restrict__ xin, const float* __restrict__ add,
    const float* __restrict__ g, const float* __restrict__ bt,
    float* __restrict__ xout)
{
    int row = blockIdx.x, t = threadIdx.x;
    float4 xv = *(const float4*)&xin[(size_t)row * E_ + t * 4];
    float4 av = *(const float4*)&add[(size_t)row * E_ + t * 4];
    xv.x += av.x; xv.y += av.y; xv.z += av.z; xv.w += av.w;
    float sum = xv.x + xv.y + xv.z + xv.w;
    #pragma unroll
    for (int off = 32; off; off >>= 1) sum += __shfl_xor(sum, off, 64);
    float mean = sum * (1.f / 256.f);
    float dx = xv.x - mean, dy = xv.y - mean, dz = xv.z - mean, dw = xv.w - mean;
    float sq = dx * dx + dy * dy + dz * dz + dw * dw;
    #pragma unroll
    for (int off = 32; off; off >>= 1) sq += __shfl_xor(sq, off, 64);
    float rstd = rsqrtf(sq * (1.f / 256.f) + 1e-12f);
    float4 gv = *(const float4*)&g[t * 4];
    float4 bv = *(const float4*)&bt[t * 4];
    float4 ov;
    ov.x = dx * rstd * gv.x + bv.x;
    ov.y = dy * rstd * gv.y + bv.y;
    ov.z = dz * rstd * gv.z + bv.z;
    ov.w = dw * rstd * gv.w + bv.w;
    *(float4*)&xout[(size_t)row * E_ + t * 4] = ov;
}

// ---------------------------------------------------------------------------
extern "C" void kernel_launch(void* const* d_in, const int* in_sizes, int n_in,
                              void* d_out, int out_size, void* d_ws, size_t ws_size,
                              hipStream_t stream) {
    const float* node_feat = (const float*)d_in[0];
    const int*   node_opc  = (const int*)d_in[1];
    const int*   dist_mat  = (const int*)d_in[2];
    const float* W_op      = (const float*)d_in[3];
    const float* W_feat    = (const float*)d_in[4];
    const float* b_feat    = (const float*)d_in[5];
    const float* W_mlp1    = (const float*)d_in[6];
    const float* b_mlp1    = (const float*)d_in[7];
    const float* W_mlp2    = (const float*)d_in[8];
    const float* b_mlp2    = (const float*)d_in[9];
    const float* cls       = (const float*)d_in[10];
    const float* dist_tab  = (const float*)d_in[11];
    const float* Wq = (const float*)d_in[12]; const float* bq = (const float*)d_in[13];
    const float* Wk = (const float*)d_in[14]; const float* bk = (const float*)d_in[15];
    const float* Wv = (const float*)d_in[16]; const float* bv = (const float*)d_in[17];
    const float* Wo = (const float*)d_in[18]; const float* bo = (const float*)d_in[19];
    const float* ln1g = (const float*)d_in[20]; const float* ln1b = (const float*)d_in[21];
    const float* Wf1 = (const float*)d_in[22]; const float* bf1 = (const float*)d_in[23];
    const float* Wf2 = (const float*)d_in[24]; const float* bf2 = (const float*)d_in[25];
    const float* ln2g = (const float*)d_in[26]; const float* ln2b = (const float*)d_in[27];

    float* out = (float*)d_out;
    float* ws  = (float*)d_ws;
    // workspace layout (fp32 elements); total ~104 MB
    float* biasb = ws;                       // 8*1024*1024
    float* x     = biasb + 8388608;          // 8192*256
    float* qb    = x  + 2097152;
    float* kb    = qb + 2097152;
    float* vb    = kb + 2097152;
    float* cb    = vb + 2097152;
    float* ffn   = cb + 2097152;             // 8192*1024
    float* hcat  = ffn;                      // alias (pre-layer only)
    float* h1    = qb;                       // alias
    float* h2    = kb;                       // alias

    bias_kernel<<<32768, 256, 0, stream>>>(dist_mat, dist_tab, biasb);
    opgather_kernel<<<8184, 256, 0, stream>>>(node_opc, W_op, hcat);
    gemm_kernel<0><<<dim3(128, 4), 256, 0, stream>>>(node_feat, 140, W_feat, 256, b_feat,
                                                     hcat + 256, 512, 8184, 256, 140);
    gemm_kernel<1><<<dim3(128, 4), 256, 0, stream>>>(hcat, 512, W_mlp1, 256, b_mlp1,
                                                     h1, 256, 8184, 256, 512);
    gemm_kernel<0><<<dim3(128, 4), 256, 0, stream>>>(h1, 256, W_mlp2, 256, b_mlp2,
                                                     h2, 256, 8184, 256, 256);
    assemble_kernel<<<8192, 256, 0, stream>>>(cls, h2, x);

    for (int l = 0; l < L_; l++) {
        const float* Wq_l = Wq + (size_t)l * 65536; const float* bq_l = bq + l * 256;
        const float* Wk_l = Wk + (size_t)l * 65536; const float* bk_l = bk + l * 256;
        const float* Wv_l = Wv + (size_t)l * 65536; const float* bv_l = bv + l * 256;
        const float* Wo_l = Wo + (size_t)l * 65536; const float* bo_l = bo + l * 256;
        const float* Wf1_l = Wf1 + (size_t)l * 262144; const float* bf1_l = bf1 + l * 1024;
        const float* Wf2_l = Wf2 + (size_t)l * 262144; const float* bf2_l = bf2 + l * 256;

        gemm_kernel<0><<<dim3(128, 4), 256, 0, stream>>>(x, 256, Wq_l, 256, bq_l, qb, 256, 8192, 256, 256);
        gemm_kernel<0><<<dim3(128, 4), 256, 0, stream>>>(x, 256, Wk_l, 256, bk_l, kb, 256, 8192, 256, 256);
        gemm_kernel<0><<<dim3(128, 4), 256, 0, stream>>>(x, 256, Wv_l, 256, bv_l, vb, 256, 8192, 256, 256);
        attn_kernel<<<1024, 64, 0, stream>>>(qb, kb, vb, biasb, cb);
        gemm_kernel<0><<<dim3(128, 4), 256, 0, stream>>>(cb, 256, Wo_l, 256, bo_l, qb, 256, 8192, 256, 256);
        ln_kernel<<<8192, 64, 0, stream>>>(x, qb, ln1g + l * 256, ln1b + l * 256, x);
        gemm_kernel<1><<<dim3(128, 16), 256, 0, stream>>>(x, 256, Wf1_l, 1024, bf1_l, ffn, 1024, 8192, 1024, 256);
        gemm_kernel<0><<<dim3(128, 4), 256, 0, stream>>>(ffn, 1024, Wf2_l, 256, bf2_l, qb, 256, 8192, 256, 1024);
        ln_kernel<<<8192, 64, 0, stream>>>(x, qb, ln2g + l * 256, ln2b + l * 256,
                                           (l == L_ - 1) ? out : x);
    }
}

// Round 4
// 2863.036 us; speedup vs baseline: 1.7397x; 1.7397x over previous
//
#include <hip/hip_runtime.h>
#include <math.h>

#define B_ 8
#define N_ 1023
#define S_ 1024
#define E_ 256
#define H_ 8
#define D_ 32
#define L_ 6
#define F_ 1024
#define NS_ 4
#define CH_ 256

// ---------------------------------------------------------------------------
// dist bias: bias[b,q,k] = table[min(d,31)] (d==-1 -> idx 32 -> JAX clamps to 31)
__global__ __launch_bounds__(256) void bias_kernel(const int* __restrict__ dm,
                                                   const float* __restrict__ table,
                                                   float* __restrict__ out) {
    int idx = blockIdx.x * 256 + threadIdx.x;          // exactly B_*S_*S_
    int d = dm[idx];
    int ii = ((unsigned)d > 30u) ? 31 : d;
    out[idx] = table[ii];
}

// op embedding gather into left half of hcat (ld 512)
__global__ __launch_bounds__(256) void opgather_kernel(const int* __restrict__ opc,
                                                       const float* __restrict__ W_op,
                                                       float* __restrict__ hcat) {
    int idx = blockIdx.x * 256 + threadIdx.x;          // 8184*256
    int row = idx >> 8, c = idx & 255;
    hcat[(size_t)row * 512 + c] = W_op[opc[row] * 256 + c];
}

// x[b,0,:]=cls ; x[b,1+n,:]=h[b*N+n,:]
__global__ __launch_bounds__(256) void assemble_kernel(const float* __restrict__ cls,
                                                       const float* __restrict__ h,
                                                       float* __restrict__ x) {
    int idx = blockIdx.x * 256 + threadIdx.x;          // B_*S_*E_
    int c = idx & 255;
    int s = (idx >> 8) & 1023;
    int b = idx >> 18;
    x[idx] = (s == 0) ? cls[c] : h[((size_t)(b * N_ + s - 1)) * 256 + c];
}

// ---------------------------------------------------------------------------
// Tiled fp32 GEMM: C[M,N] = epi(A[M,K] @ B[K,N] + bias[N])
// BM=BN=64, BK=16, 256 threads, 4x4 per-thread tile, float4 LDS fragments.
// EPI: 0 = none, 1 = exact GELU.  GUARD: 0 = M,K exact multiples of tile.
template<int EPI, int GUARD>
__global__ __launch_bounds__(256) void gemm_kernel(
    const float* __restrict__ A, int lda,
    const float* __restrict__ Bm, int ldb,
    const float* __restrict__ bias,
    float* __restrict__ C, int ldc,
    int M, int N, int K)
{
    __shared__ float As[16][68];   // transposed: As[k][m]
    __shared__ float Bs[16][68];   // Bs[k][n]
    const int t = threadIdx.x;
    const int m0 = blockIdx.x * 64, n0 = blockIdx.y * 64;
    const int tx = t & 15, ty = t >> 4;
    const int tm = ty * 4, tn = tx * 4;
    float acc[4][4] = {};
    const int am = t >> 2, ak = (t & 3) * 4;
    const int bkr = t >> 4, bn4 = (t & 15) * 4;
    const int nt = (K + 15) >> 4;
    for (int kt = 0; kt < nt; kt++) {
        int k0 = kt * 16;
        if (GUARD) {
            #pragma unroll
            for (int j = 0; j < 4; j++) {
                int kk = k0 + ak + j;
                float v = 0.f;
                if (m0 + am < M && kk < K) v = A[(size_t)(m0 + am) * lda + kk];
                As[ak + j][am] = v;
            }
            float4 v = {0.f, 0.f, 0.f, 0.f};
            if (k0 + bkr < K) v = *(const float4*)&Bm[(size_t)(k0 + bkr) * ldb + n0 + bn4];
            *(float4*)&Bs[bkr][bn4] = v;
        } else {
            float4 av4 = *(const float4*)&A[(size_t)(m0 + am) * lda + k0 + ak];
            As[ak + 0][am] = av4.x;
            As[ak + 1][am] = av4.y;
            As[ak + 2][am] = av4.z;
            As[ak + 3][am] = av4.w;
            *(float4*)&Bs[bkr][bn4] =
                *(const float4*)&Bm[(size_t)(k0 + bkr) * ldb + n0 + bn4];
        }
        __syncthreads();
        #pragma unroll
        for (int kk = 0; kk < 16; kk++) {
            float4 a = *(const float4*)&As[kk][tm];
            float4 b = *(const float4*)&Bs[kk][tn];
            float av[4] = {a.x, a.y, a.z, a.w};
            float bw[4] = {b.x, b.y, b.z, b.w};
            #pragma unroll
            for (int i = 0; i < 4; i++)
                #pragma unroll
                for (int j = 0; j < 4; j++)
                    acc[i][j] = fmaf(av[i], bw[j], acc[i][j]);
        }
        __syncthreads();
    }
    #pragma unroll
    for (int j = 0; j < 4; j++) {
        float bv = bias ? bias[n0 + tn + j] : 0.f;
        #pragma unroll
        for (int i = 0; i < 4; i++) {
            int m = m0 + tm + i;
            if (!GUARD || m < M) {
                float v = acc[i][j] + bv;
                if (EPI == 1) v = 0.5f * v * (1.f + erff(v * 0.70710678118654752f));
                C[(size_t)m * ldc + n0 + tn + j] = v;
            }
        }
    }
}

// ---------------------------------------------------------------------------
// Flash attention, split-K over NS_=4 chunks of CH_=256 keys.
// Block = 64 threads (1 wave); each thread owns TWO query rows (q0, q0+64)
// so each LDS K/V float4 read feeds 8 FMA. Writes unnormalized partial o
// plus (m, l) per chunk; attn_merge combines.
__global__ __launch_bounds__(64, 2) void attn_kernel(
    const float* __restrict__ q, const float* __restrict__ k,
    const float* __restrict__ v, const float* __restrict__ bias,
    float* __restrict__ opart, float* __restrict__ ml)
{
    __shared__ float Ks[32][36];
    __shared__ float Vs[32][36];
    const int t = threadIdx.x;
    const int bid = blockIdx.x;            // 2048 = b(3)|h(3)|qt(3)|ch(2)
    const int ch = bid & 3;
    const int qt = (bid >> 2) & 7;
    const int h  = (bid >> 5) & 7;
    const int b  = bid >> 8;
    const int q0 = qt * 128 + t;
    const float scale = 0.17677669529663687f;

    float4 qa[8], qb2[8];
    {
        const float* qp = q + ((size_t)(b * S_ + q0)) * E_ + h * D_;
        #pragma unroll
        for (int i = 0; i < 8; i++) {
            float4 tv = *(const float4*)&qp[i * 4];
            qa[i].x = tv.x * scale; qa[i].y = tv.y * scale;
            qa[i].z = tv.z * scale; qa[i].w = tv.w * scale;
            float4 tw = *(const float4*)&qp[(size_t)64 * E_ + i * 4];
            qb2[i].x = tw.x * scale; qb2[i].y = tw.y * scale;
            qb2[i].z = tw.z * scale; qb2[i].w = tw.w * scale;
        }
    }
    float4 oa[8] = {}, ob[8] = {};
    float ma = -3e38f, la = 0.f, mb = -3e38f, lb = 0.f;
    const float* bpa = bias + ((size_t)(b * S_ + q0)) * S_ + ch * CH_;
    const float* bpb = bpa + (size_t)64 * S_;
    const int r = t >> 1, c0 = (t & 1) * 16;
    const int kb0 = ch * CH_;

    for (int kt = 0; kt < CH_; kt += 32) {
        const float* kp = k + ((size_t)(b * S_ + kb0 + kt + r)) * E_ + h * D_ + c0;
        const float* vp = v + ((size_t)(b * S_ + kb0 + kt + r)) * E_ + h * D_ + c0;
        #pragma unroll
        for (int i = 0; i < 4; i++) {
            *(float4*)&Ks[r][c0 + i * 4] = *(const float4*)&kp[i * 4];
            *(float4*)&Vs[r][c0 + i * 4] = *(const float4*)&vp[i * 4];
        }
        __syncthreads();

        float sa[32], sb[32];
        #pragma unroll
        for (int k4 = 0; k4 < 8; k4++) {
            float4 b4 = *(const float4*)&bpa[kt + k4 * 4];
            sa[k4 * 4 + 0] = b4.x; sa[k4 * 4 + 1] = b4.y;
            sa[k4 * 4 + 2] = b4.z; sa[k4 * 4 + 3] = b4.w;
            float4 c4 = *(const float4*)&bpb[kt + k4 * 4];
            sb[k4 * 4 + 0] = c4.x; sb[k4 * 4 + 1] = c4.y;
            sb[k4 * 4 + 2] = c4.z; sb[k4 * 4 + 3] = c4.w;
        }
        #pragma unroll
        for (int d4 = 0; d4 < 8; d4++) {
            float4 qva = qa[d4], qvb = qb2[d4];
            #pragma unroll
            for (int kk = 0; kk < 32; kk++) {
                float4 kv = *(const float4*)&Ks[kk][d4 * 4];
                sa[kk] = fmaf(qva.x, kv.x, sa[kk]);
                sa[kk] = fmaf(qva.y, kv.y, sa[kk]);
                sa[kk] = fmaf(qva.z, kv.z, sa[kk]);
                sa[kk] = fmaf(qva.w, kv.w, sa[kk]);
                sb[kk] = fmaf(qvb.x, kv.x, sb[kk]);
                sb[kk] = fmaf(qvb.y, kv.y, sb[kk]);
                sb[kk] = fmaf(qvb.z, kv.z, sb[kk]);
                sb[kk] = fmaf(qvb.w, kv.w, sb[kk]);
            }
        }
        float tma = sa[0], tmb = sb[0];
        #pragma unroll
        for (int kk = 1; kk < 32; kk++) {
            tma = fmaxf(tma, sa[kk]); tmb = fmaxf(tmb, sb[kk]);
        }
        float mna = fmaxf(ma, tma), mnb = fmaxf(mb, tmb);
        float ca = __expf(ma - mna), cb = __expf(mb - mnb);
        la *= ca; lb *= cb;
        #pragma unroll
        for (int d4 = 0; d4 < 8; d4++) {
            oa[d4].x *= ca; oa[d4].y *= ca; oa[d4].z *= ca; oa[d4].w *= ca;
            ob[d4].x *= cb; ob[d4].y *= cb; ob[d4].z *= cb; ob[d4].w *= cb;
        }
        float psa = 0.f, psb = 0.f;
        #pragma unroll
        for (int kk = 0; kk < 32; kk++) {
            sa[kk] = __expf(sa[kk] - mna); psa += sa[kk];
            sb[kk] = __expf(sb[kk] - mnb); psb += sb[kk];
        }
        la += psa; lb += psb;
        #pragma unroll
        for (int kk = 0; kk < 32; kk++) {
            float pa = sa[kk], pb = sb[kk];
            #pragma unroll
            for (int d4 = 0; d4 < 8; d4++) {
                float4 vv = *(const float4*)&Vs[kk][d4 * 4];
                oa[d4].x = fmaf(pa, vv.x, oa[d4].x);
                oa[d4].y = fmaf(pa, vv.y, oa[d4].y);
                oa[d4].z = fmaf(pa, vv.z, oa[d4].z);
                oa[d4].w = fmaf(pa, vv.w, oa[d4].w);
                ob[d4].x = fmaf(pb, vv.x, ob[d4].x);
                ob[d4].y = fmaf(pb, vv.y, ob[d4].y);
                ob[d4].z = fmaf(pb, vv.z, ob[d4].z);
                ob[d4].w = fmaf(pb, vv.w, ob[d4].w);
            }
        }
        ma = mna; mb = mnb;
        __syncthreads();
    }
    const int rowa = ((b * 8 + h) << 10) + q0;
    const int rowb = rowa + 64;
    float* pa = opart + (size_t)rowa * 128 + ch * 32;
    float* pb = opart + (size_t)rowb * 128 + ch * 32;
    #pragma unroll
    for (int d4 = 0; d4 < 8; d4++) {
        *(float4*)&pa[d4 * 4] = oa[d4];
        *(float4*)&pb[d4 * 4] = ob[d4];
    }
    ml[(size_t)rowa * 8 + ch * 2 + 0] = ma;
    ml[(size_t)rowa * 8 + ch * 2 + 1] = la;
    ml[(size_t)rowb * 8 + ch * 2 + 0] = mb;
    ml[(size_t)rowb * 8 + ch * 2 + 1] = lb;
}

// Combine the NS_ partials for each of the 65536 (b,h,s) rows.
__global__ __launch_bounds__(256) void attn_merge(
    const float* __restrict__ opart, const float* __restrict__ ml,
    float* __restrict__ ctx)
{
    int row = blockIdx.x * 256 + threadIdx.x;  // 65536 = b(3)|h(3)|s(10)
    int b = row >> 13;
    int h = (row >> 10) & 7;
    int s = row & 1023;
    const float* mp = ml + (size_t)row * 8;
    float m0 = mp[0], l0 = mp[1], m1 = mp[2], l1 = mp[3];
    float m2 = mp[4], l2 = mp[5], m3 = mp[6], l3 = mp[7];
    float M = fmaxf(fmaxf(m0, m1), fmaxf(m2, m3));
    float w0 = __expf(m0 - M), w1 = __expf(m1 - M);
    float w2 = __expf(m2 - M), w3 = __expf(m3 - M);
    float inv = 1.f / (l0 * w0 + l1 * w1 + l2 * w2 + l3 * w3);
    const float* pp = opart + (size_t)row * 128;
    float* op = ctx + ((size_t)(b * S_ + s)) * E_ + h * D_;
    #pragma unroll
    for (int d4 = 0; d4 < 8; d4++) {
        float4 a0 = *(const float4*)&pp[d4 * 4];
        float4 a1 = *(const float4*)&pp[32 + d4 * 4];
        float4 a2 = *(const float4*)&pp[64 + d4 * 4];
        float4 a3 = *(const float4*)&pp[96 + d4 * 4];
        float4 o;
        o.x = (a0.x * w0 + a1.x * w1 + a2.x * w2 + a3.x * w3) * inv;
        o.y = (a0.y * w0 + a1.y * w1 + a2.y * w2 + a3.y * w3) * inv;
        o.z = (a0.z * w0 + a1.z * w1 + a2.z * w2 + a3.z * w3) * inv;
        o.w = (a0.w * w0 + a1.w * w1 + a2.w * w2 + a3.w * w3) * inv;
        *(float4*)&op[d4 * 4] = o;
    }
}

// ---------------------------------------------------------------------------
// xout = LN(xin + add) * g + b   (one wave per 256-elem row)
__global__ __launch_bounds__(64) void ln_kernel(
    const float* __restrict__ xin, const float* __restrict__ add,
    const float* __restrict__ g, const float* __restrict__ bt,
    float* __restrict__ xout)
{
    int row = blockIdx.x, t = threadIdx.x;
    float4 xv = *(const float4*)&xin[(size_t)row * E_ + t * 4];
    float4 av = *(const float4*)&add[(size_t)row * E_ + t * 4];
    xv.x += av.x; xv.y += av.y; xv.z += av.z; xv.w += av.w;
    float sum = xv.x + xv.y + xv.z + xv.w;
    #pragma unroll
    for (int off = 32; off; off >>= 1) sum += __shfl_xor(sum, off, 64);
    float mean = sum * (1.f / 256.f);
    float dx = xv.x - mean, dy = xv.y - mean, dz = xv.z - mean, dw = xv.w - mean;
    float sq = dx * dx + dy * dy + dz * dz + dw * dw;
    #pragma unroll
    for (int off = 32; off; off >>= 1) sq += __shfl_xor(sq, off, 64);
    float rstd = rsqrtf(sq * (1.f / 256.f) + 1e-12f);
    float4 gv = *(const float4*)&g[t * 4];
    float4 bv = *(const float4*)&bt[t * 4];
    float4 ov;
    ov.x = dx * rstd * gv.x + bv.x;
    ov.y = dy * rstd * gv.y + bv.y;
    ov.z = dz * rstd * gv.z + bv.z;
    ov.w = dw * rstd * gv.w + bv.w;
    *(float4*)&xout[(size_t)row * E_ + t * 4] = ov;
}

// ---------------------------------------------------------------------------
extern "C" void kernel_launch(void* const* d_in, const int* in_sizes, int n_in,
                              void* d_out, int out_size, void* d_ws, size_t ws_size,
                              hipStream_t stream) {
    const float* node_feat = (const float*)d_in[0];
    const int*   node_opc  = (const int*)d_in[1];
    const int*   dist_mat  = (const int*)d_in[2];
    const float* W_op      = (const float*)d_in[3];
    const float* W_feat    = (const float*)d_in[4];
    const float* b_feat    = (const float*)d_in[5];
    const float* W_mlp1    = (const float*)d_in[6];
    const float* b_mlp1    = (const float*)d_in[7];
    const float* W_mlp2    = (const float*)d_in[8];
    const float* b_mlp2    = (const float*)d_in[9];
    const float* cls       = (const float*)d_in[10];
    const float* dist_tab  = (const float*)d_in[11];
    const float* Wq = (const float*)d_in[12]; const float* bq = (const float*)d_in[13];
    const float* Wk = (const float*)d_in[14]; const float* bk = (const float*)d_in[15];
    const float* Wv = (const float*)d_in[16]; const float* bv = (const float*)d_in[17];
    const float* Wo = (const float*)d_in[18]; const float* bo = (const float*)d_in[19];
    const float* ln1g = (const float*)d_in[20]; const float* ln1b = (const float*)d_in[21];
    const float* Wf1 = (const float*)d_in[22]; const float* bf1 = (const float*)d_in[23];
    const float* Wf2 = (const float*)d_in[24]; const float* bf2 = (const float*)d_in[25];
    const float* ln2g = (const float*)d_in[26]; const float* ln2b = (const float*)d_in[27];

    float* out = (float*)d_out;
    float* ws  = (float*)d_ws;
    // workspace layout (fp32 elements); ~111 MB
    float* biasb = ws;                       // 8*1024*1024
    float* x     = biasb + 8388608;          // 8192*256
    float* qb    = x  + 2097152;
    float* kb    = qb + 2097152;
    float* vb    = kb + 2097152;
    float* cb    = vb + 2097152;
    float* ffn   = cb + 2097152;             // 8192*1024
    float* mlbuf = ffn + 8388608;            // 65536*8
    float* opart = ffn;                      // alias: attn partials (exactly 8388608)
    float* hcat  = ffn;                      // alias (pre-layer only)
    float* h1    = qb;                       // alias
    float* h2    = kb;                       // alias

    bias_kernel<<<32768, 256, 0, stream>>>(dist_mat, dist_tab, biasb);
    opgather_kernel<<<8184, 256, 0, stream>>>(node_opc, W_op, hcat);
    gemm_kernel<0, 1><<<dim3(128, 4), 256, 0, stream>>>(node_feat, 140, W_feat, 256, b_feat,
                                                        hcat + 256, 512, 8184, 256, 140);
    gemm_kernel<1, 1><<<dim3(128, 4), 256, 0, stream>>>(hcat, 512, W_mlp1, 256, b_mlp1,
                                                        h1, 256, 8184, 256, 512);
    gemm_kernel<0, 1><<<dim3(128, 4), 256, 0, stream>>>(h1, 256, W_mlp2, 256, b_mlp2,
                                                        h2, 256, 8184, 256, 256);
    assemble_kernel<<<8192, 256, 0, stream>>>(cls, h2, x);

    for (int l = 0; l < L_; l++) {
        const float* Wq_l = Wq + (size_t)l * 65536; const float* bq_l = bq + l * 256;
        const float* Wk_l = Wk + (size_t)l * 65536; const float* bk_l = bk + l * 256;
        const float* Wv_l = Wv + (size_t)l * 65536; const float* bv_l = bv + l * 256;
        const float* Wo_l = Wo + (size_t)l * 65536; const float* bo_l = bo + l * 256;
        const float* Wf1_l = Wf1 + (size_t)l * 262144; const float* bf1_l = bf1 + l * 1024;
        const float* Wf2_l = Wf2 + (size_t)l * 262144; const float* bf2_l = bf2 + l * 256;

        gemm_kernel<0, 0><<<dim3(128, 4), 256, 0, stream>>>(x, 256, Wq_l, 256, bq_l, qb, 256, 8192, 256, 256);
        gemm_kernel<0, 0><<<dim3(128, 4), 256, 0, stream>>>(x, 256, Wk_l, 256, bk_l, kb, 256, 8192, 256, 256);
        gemm_kernel<0, 0><<<dim3(128, 4), 256, 0, stream>>>(x, 256, Wv_l, 256, bv_l, vb, 256, 8192, 256, 256);
        attn_kernel<<<2048, 64, 0, stream>>>(qb, kb, vb, biasb, opart, mlbuf);
        attn_merge<<<256, 256, 0, stream>>>(opart, mlbuf, cb);
        gemm_kernel<0, 0><<<dim3(128, 4), 256, 0, stream>>>(cb, 256, Wo_l, 256, bo_l, qb, 256, 8192, 256, 256);
        ln_kernel<<<8192, 64, 0, stream>>>(x, qb, ln1g + l * 256, ln1b + l * 256, x);
        gemm_kernel<1, 0><<<dim3(128, 16), 256, 0, stream>>>(x, 256, Wf1_l, 1024, bf1_l, ffn, 1024, 8192, 1024, 256);
        gemm_kernel<0, 0><<<dim3(128, 4), 256, 0, stream>>>(ffn, 1024, Wf2_l, 256, bf2_l, qb, 256, 8192, 256, 1024);
        ln_kernel<<<8192, 64, 0, stream>>>(x, qb, ln2g + l * 256, ln2b + l * 256,
                                           (l == L_ - 1) ? out : x);
    }
}

// Round 6
// 1793.872 us; speedup vs baseline: 2.7766x; 1.5960x over previous
//
#include <hip/hip_runtime.h>
#include <math.h>

#define B_ 8
#define N_ 1023
#define S_ 1024
#define E_ 256
#define H_ 8
#define D_ 32
#define L_ 6
#define F_ 1024
#define NS_ 4
#define CH_ 256

typedef __attribute__((ext_vector_type(8))) short bf16x8;
typedef __attribute__((ext_vector_type(4))) float f32x4;

__device__ __forceinline__ ushort f2b(float x) {
    unsigned u = __float_as_uint(x);
    return (ushort)((u + 0x7fffu + ((u >> 16) & 1u)) >> 16);
}

// ---------------------------------------------------------------------------
// dist bias: bias[b,q,k] = table[min(d,31)] (d==-1 -> idx 32 -> JAX clamps to 31)
__global__ __launch_bounds__(256) void bias_kernel(const int* __restrict__ dm,
                                                   const float* __restrict__ table,
                                                   float* __restrict__ out) {
    int idx = blockIdx.x * 256 + threadIdx.x;          // exactly B_*S_*S_
    int d = dm[idx];
    int ii = ((unsigned)d > 30u) ? 31 : d;
    out[idx] = table[ii];
}

// op embedding gather into left half of hcat (ld 512)
__global__ __launch_bounds__(256) void opgather_kernel(const int* __restrict__ opc,
                                                       const float* __restrict__ W_op,
                                                       float* __restrict__ hcat) {
    int idx = blockIdx.x * 256 + threadIdx.x;          // 8184*256
    int row = idx >> 8, c = idx & 255;
    hcat[(size_t)row * 512 + c] = W_op[opc[row] * 256 + c];
}

// x[b,0,:]=cls ; x[b,1+n,:]=h[b*N+n,:]   (also emits bf16 copy)
__global__ __launch_bounds__(256) void assemble_kernel(const float* __restrict__ cls,
                                                       const float* __restrict__ h,
                                                       float* __restrict__ x,
                                                       ushort* __restrict__ xb) {
    int idx = blockIdx.x * 256 + threadIdx.x;          // B_*S_*E_
    int c = idx & 255;
    int s = (idx >> 8) & 1023;
    int b = idx >> 18;
    float v = (s == 0) ? cls[c] : h[((size_t)(b * N_ + s - 1)) * 256 + c];
    x[idx] = v;
    xb[idx] = f2b(v);
}

// ---------------------------------------------------------------------------
// Weight convert + transpose: out[l][n][k] = bf16(in[l][k][n]).
// idx fastest over k -> coalesced 2B writes; reads served by L2.
__global__ __launch_bounds__(256) void wconv_t(const float* __restrict__ in,
                                               ushort* __restrict__ out,
                                               int K, int Nn) {
    int idx = blockIdx.x * 256 + threadIdx.x;
    int per = K * Nn;
    int lw = idx / per, rem = idx - lw * per;
    int n = rem / K, k = rem - n * K;
    out[idx] = f2b(in[(size_t)lw * per + (size_t)k * Nn + n]);
}

// ---------------------------------------------------------------------------
// MFMA bf16 GEMM: C[M,N] = epi(A[M,K]_bf16 @ B[K,N] + bias[N])
// B supplied TRANSPOSED as Bt[N][K] bf16. BM=BN=64, BK=32, 256 thr = 4 waves
// (2x2), each wave 32x32 via 2x2 frags of v_mfma_f32_16x16x32_bf16.
// EPI 0: fp32 out. EPI 1: exact GELU, bf16 out.
template<int EPI>
__global__ __launch_bounds__(256) void mgemm(
    const ushort* __restrict__ A, const ushort* __restrict__ Bt,
    const float* __restrict__ bias, void* __restrict__ C,
    int M, int Nn, int K)
{
    __shared__ ushort As[64 * 32];
    __shared__ ushort Bs[64 * 32];
    const int t = threadIdx.x;
    const int m0 = blockIdx.x * 64, n0 = blockIdx.y * 64;
    const int l = t & 63, w = t >> 6;
    const int wr = (w >> 1) * 32, wc = (w & 1) * 32;
    const int sr = t >> 2, sc = (t & 3) * 8;   // staging: row, 8-elem chunk
    const int l15 = l & 15, lk = (l >> 4) * 8;

    f32x4 zero = {0.f, 0.f, 0.f, 0.f};
    f32x4 acc00 = zero, acc01 = zero, acc10 = zero, acc11 = zero;

    const ushort* ap = A + (size_t)(m0 + sr) * K + sc;
    const ushort* bp = Bt + (size_t)(n0 + sr) * K + sc;
    bf16x8 ra = *(const bf16x8*)ap;
    bf16x8 rb = *(const bf16x8*)bp;

    for (int kt = 0; kt < K; kt += 32) {
        *(bf16x8*)&As[sr * 32 + sc] = ra;
        *(bf16x8*)&Bs[sr * 32 + sc] = rb;
        __syncthreads();
        if (kt + 32 < K) {                       // prefetch next tile into regs
            ra = *(const bf16x8*)(ap + kt + 32);
            rb = *(const bf16x8*)(bp + kt + 32);
        }
        bf16x8 a0 = *(bf16x8*)&As[(wr + l15) * 32 + lk];
        bf16x8 a1 = *(bf16x8*)&As[(wr + 16 + l15) * 32 + lk];
        bf16x8 b0 = *(bf16x8*)&Bs[(wc + l15) * 32 + lk];
        bf16x8 b1 = *(bf16x8*)&Bs[(wc + 16 + l15) * 32 + lk];
        acc00 = __builtin_amdgcn_mfma_f32_16x16x32_bf16(a0, b0, acc00, 0, 0, 0);
        acc01 = __builtin_amdgcn_mfma_f32_16x16x32_bf16(a0, b1, acc01, 0, 0, 0);
        acc10 = __builtin_amdgcn_mfma_f32_16x16x32_bf16(a1, b0, acc10, 0, 0, 0);
        acc11 = __builtin_amdgcn_mfma_f32_16x16x32_bf16(a1, b1, acc11, 0, 0, 0);
        __syncthreads();
    }
    // D mapping: col = lane&15, row = (lane>>4)*4 + r   [m89-verified]
    const int cn = n0 + wc + l15;
    const int rbase = m0 + wr + (l >> 4) * 4;
    float bv0 = bias[cn], bv1 = bias[cn + 16];
    #pragma unroll
    for (int i = 0; i < 2; i++) {
        f32x4 aj0 = i ? acc10 : acc00;
        f32x4 aj1 = i ? acc11 : acc01;
        #pragma unroll
        for (int r = 0; r < 4; r++) {
            int row = rbase + i * 16 + r;
            float v0 = aj0[r] + bv0;
            float v1 = aj1[r] + bv1;
            if (EPI == 1) {
                v0 = 0.5f * v0 * (1.f + erff(v0 * 0.70710678118654752f));
                v1 = 0.5f * v1 * (1.f + erff(v1 * 0.70710678118654752f));
                ((ushort*)C)[(size_t)row * Nn + cn] = f2b(v0);
                ((ushort*)C)[(size_t)row * Nn + cn + 16] = f2b(v1);
            } else {
                ((float*)C)[(size_t)row * Nn + cn] = v0;
                ((float*)C)[(size_t)row * Nn + cn + 16] = v1;
            }
        }
    }
}

// ---------------------------------------------------------------------------
// Tiled fp32 GEMM (guarded) — pre-layer only (M=8184, K=140/512/256).
template<int EPI>
__global__ __launch_bounds__(256) void gemm_kernel(
    const float* __restrict__ A, int lda,
    const float* __restrict__ Bm, int ldb,
    const float* __restrict__ bias,
    float* __restrict__ C, int ldc,
    int M, int Nn, int K)
{
    __shared__ float As[16][68];
    __shared__ float Bs[16][68];
    const int t = threadIdx.x;
    const int m0 = blockIdx.x * 64, n0 = blockIdx.y * 64;
    const int tx = t & 15, ty = t >> 4;
    const int tm = ty * 4, tn = tx * 4;
    float acc[4][4] = {};
    const int am = t >> 2, ak = (t & 3) * 4;
    const int bkr = t >> 4, bn4 = (t & 15) * 4;
    const int nt = (K + 15) >> 4;
    for (int kt = 0; kt < nt; kt++) {
        int k0 = kt * 16;
        #pragma unroll
        for (int j = 0; j < 4; j++) {
            int kk = k0 + ak + j;
            float v = 0.f;
            if (m0 + am < M && kk < K) v = A[(size_t)(m0 + am) * lda + kk];
            As[ak + j][am] = v;
        }
        {
            float4 v = {0.f, 0.f, 0.f, 0.f};
            if (k0 + bkr < K) v = *(const float4*)&Bm[(size_t)(k0 + bkr) * ldb + n0 + bn4];
            *(float4*)&Bs[bkr][bn4] = v;
        }
        __syncthreads();
        #pragma unroll
        for (int kk = 0; kk < 16; kk++) {
            float4 a = *(const float4*)&As[kk][tm];
            float4 b = *(const float4*)&Bs[kk][tn];
            float av[4] = {a.x, a.y, a.z, a.w};
            float bw[4] = {b.x, b.y, b.z, b.w};
            #pragma unroll
            for (int i = 0; i < 4; i++)
                #pragma unroll
                for (int j = 0; j < 4; j++)
                    acc[i][j] = fmaf(av[i], bw[j], acc[i][j]);
        }
        __syncthreads();
    }
    #pragma unroll
    for (int j = 0; j < 4; j++) {
        float bv = bias ? bias[n0 + tn + j] : 0.f;
        #pragma unroll
        for (int i = 0; i < 4; i++) {
            int m = m0 + tm + i;
            if (m < M) {
                float v = acc[i][j] + bv;
                if (EPI == 1) v = 0.5f * v * (1.f + erff(v * 0.70710678118654752f));
                C[(size_t)m * ldc + n0 + tn + j] = v;
            }
        }
    }
}

// ---------------------------------------------------------------------------
// Flash attention, split-K over NS_=4 chunks of CH_=256 keys (unchanged).
__global__ __launch_bounds__(64, 2) void attn_kernel(
    const float* __restrict__ q, const float* __restrict__ k,
    const float* __restrict__ v, const float* __restrict__ bias,
    float* __restrict__ opart, float* __restrict__ ml)
{
    __shared__ float Ks[32][36];
    __shared__ float Vs[32][36];
    const int t = threadIdx.x;
    const int bid = blockIdx.x;            // 2048 = b(3)|h(3)|qt(3)|ch(2)
    const int ch = bid & 3;
    const int qt = (bid >> 2) & 7;
    const int h  = (bid >> 5) & 7;
    const int b  = bid >> 8;
    const int q0 = qt * 128 + t;
    const float scale = 0.17677669529663687f;

    float4 qa[8], qb2[8];
    {
        const float* qp = q + ((size_t)(b * S_ + q0)) * E_ + h * D_;
        #pragma unroll
        for (int i = 0; i < 8; i++) {
            float4 tv = *(const float4*)&qp[i * 4];
            qa[i].x = tv.x * scale; qa[i].y = tv.y * scale;
            qa[i].z = tv.z * scale; qa[i].w = tv.w * scale;
            float4 tw = *(const float4*)&qp[(size_t)64 * E_ + i * 4];
            qb2[i].x = tw.x * scale; qb2[i].y = tw.y * scale;
            qb2[i].z = tw.z * scale; qb2[i].w = tw.w * scale;
        }
    }
    float4 oa[8] = {}, ob[8] = {};
    float ma = -3e38f, la = 0.f, mb = -3e38f, lb = 0.f;
    const float* bpa = bias + ((size_t)(b * S_ + q0)) * S_ + ch * CH_;
    const float* bpb = bpa + (size_t)64 * S_;
    const int r = t >> 1, c0 = (t & 1) * 16;
    const int kb0 = ch * CH_;

    for (int kt = 0; kt < CH_; kt += 32) {
        const float* kp = k + ((size_t)(b * S_ + kb0 + kt + r)) * E_ + h * D_ + c0;
        const float* vp = v + ((size_t)(b * S_ + kb0 + kt + r)) * E_ + h * D_ + c0;
        #pragma unroll
        for (int i = 0; i < 4; i++) {
            *(float4*)&Ks[r][c0 + i * 4] = *(const float4*)&kp[i * 4];
            *(float4*)&Vs[r][c0 + i * 4] = *(const float4*)&vp[i * 4];
        }
        __syncthreads();

        float sa[32], sb[32];
        #pragma unroll
        for (int k4 = 0; k4 < 8; k4++) {
            float4 b4 = *(const float4*)&bpa[kt + k4 * 4];
            sa[k4 * 4 + 0] = b4.x; sa[k4 * 4 + 1] = b4.y;
            sa[k4 * 4 + 2] = b4.z; sa[k4 * 4 + 3] = b4.w;
            float4 c4 = *(const float4*)&bpb[kt + k4 * 4];
            sb[k4 * 4 + 0] = c4.x; sb[k4 * 4 + 1] = c4.y;
            sb[k4 * 4 + 2] = c4.z; sb[k4 * 4 + 3] = c4.w;
        }
        #pragma unroll
        for (int d4 = 0; d4 < 8; d4++) {
            float4 qva = qa[d4], qvb = qb2[d4];
            #pragma unroll
            for (int kk = 0; kk < 32; kk++) {
                float4 kv = *(const float4*)&Ks[kk][d4 * 4];
                sa[kk] = fmaf(qva.x, kv.x, sa[kk]);
                sa[kk] = fmaf(qva.y, kv.y, sa[kk]);
                sa[kk] = fmaf(qva.z, kv.z, sa[kk]);
                sa[kk] = fmaf(qva.w, kv.w, sa[kk]);
                sb[kk] = fmaf(qvb.x, kv.x, sb[kk]);
                sb[kk] = fmaf(qvb.y, kv.y, sb[kk]);
                sb[kk] = fmaf(qvb.z, kv.z, sb[kk]);
                sb[kk] = fmaf(qvb.w, kv.w, sb[kk]);
            }
        }
        float tma = sa[0], tmb = sb[0];
        #pragma unroll
        for (int kk = 1; kk < 32; kk++) {
            tma = fmaxf(tma, sa[kk]); tmb = fmaxf(tmb, sb[kk]);
        }
        float mna = fmaxf(ma, tma), mnb = fmaxf(mb, tmb);
        float ca = __expf(ma - mna), cb = __expf(mb - mnb);
        la *= ca; lb *= cb;
        #pragma unroll
        for (int d4 = 0; d4 < 8; d4++) {
            oa[d4].x *= ca; oa[d4].y *= ca; oa[d4].z *= ca; oa[d4].w *= ca;
            ob[d4].x *= cb; ob[d4].y *= cb; ob[d4].z *= cb; ob[d4].w *= cb;
        }
        float psa = 0.f, psb = 0.f;
        #pragma unroll
        for (int kk = 0; kk < 32; kk++) {
            sa[kk] = __expf(sa[kk] - mna); psa += sa[kk];
            sb[kk] = __expf(sb[kk] - mnb); psb += sb[kk];
        }
        la += psa; lb += psb;
        #pragma unroll
        for (int kk = 0; kk < 32; kk++) {
            float pa = sa[kk], pb = sb[kk];
            #pragma unroll
            for (int d4 = 0; d4 < 8; d4++) {
                float4 vv = *(const float4*)&Vs[kk][d4 * 4];
                oa[d4].x = fmaf(pa, vv.x, oa[d4].x);
                oa[d4].y = fmaf(pa, vv.y, oa[d4].y);
                oa[d4].z = fmaf(pa, vv.z, oa[d4].z);
                oa[d4].w = fmaf(pa, vv.w, oa[d4].w);
                ob[d4].x = fmaf(pb, vv.x, ob[d4].x);
                ob[d4].y = fmaf(pb, vv.y, ob[d4].y);
                ob[d4].z = fmaf(pb, vv.z, ob[d4].z);
                ob[d4].w = fmaf(pb, vv.w, ob[d4].w);
            }
        }
        ma = mna; mb = mnb;
        __syncthreads();
    }
    const int rowa = ((b * 8 + h) << 10) + q0;
    const int rowb = rowa + 64;
    float* pa = opart + (size_t)rowa * 128 + ch * 32;
    float* pb = opart + (size_t)rowb * 128 + ch * 32;
    #pragma unroll
    for (int d4 = 0; d4 < 8; d4++) {
        *(float4*)&pa[d4 * 4] = oa[d4];
        *(float4*)&pb[d4 * 4] = ob[d4];
    }
    ml[(size_t)rowa * 8 + ch * 2 + 0] = ma;
    ml[(size_t)rowa * 8 + ch * 2 + 1] = la;
    ml[(size_t)rowb * 8 + ch * 2 + 0] = mb;
    ml[(size_t)rowb * 8 + ch * 2 + 1] = lb;
}

// Combine the NS_ partials; emit ctx as bf16 (consumed only by Wo mgemm).
__global__ __launch_bounds__(256) void attn_merge(
    const float* __restrict__ opart, const float* __restrict__ ml,
    ushort* __restrict__ ctxb)
{
    int row = blockIdx.x * 256 + threadIdx.x;  // 65536 = b(3)|h(3)|s(10)
    int b = row >> 13;
    int h = (row >> 10) & 7;
    int s = row & 1023;
    const float* mp = ml + (size_t)row * 8;
    float m0 = mp[0], l0 = mp[1], m1 = mp[2], l1 = mp[3];
    float m2 = mp[4], l2 = mp[5], m3 = mp[6], l3 = mp[7];
    float M = fmaxf(fmaxf(m0, m1), fmaxf(m2, m3));
    float w0 = __expf(m0 - M), w1 = __expf(m1 - M);
    float w2 = __expf(m2 - M), w3 = __expf(m3 - M);
    float inv = 1.f / (l0 * w0 + l1 * w1 + l2 * w2 + l3 * w3);
    const float* pp = opart + (size_t)row * 128;
    ushort* op = ctxb + ((size_t)(b * S_ + s)) * E_ + h * D_;
    #pragma unroll
    for (int d4 = 0; d4 < 8; d4++) {
        float4 a0 = *(const float4*)&pp[d4 * 4];
        float4 a1 = *(const float4*)&pp[32 + d4 * 4];
        float4 a2 = *(const float4*)&pp[64 + d4 * 4];
        float4 a3 = *(const float4*)&pp[96 + d4 * 4];
        ushort4 o;
        o.x = f2b((a0.x * w0 + a1.x * w1 + a2.x * w2 + a3.x * w3) * inv);
        o.y = f2b((a0.y * w0 + a1.y * w1 + a2.y * w2 + a3.y * w3) * inv);
        o.z = f2b((a0.z * w0 + a1.z * w1 + a2.z * w2 + a3.z * w3) * inv);
        o.w = f2b((a0.w * w0 + a1.w * w1 + a2.w * w2 + a3.w * w3) * inv);
        *(ushort4*)&op[d4 * 4] = o;
    }
}

// ---------------------------------------------------------------------------
// xout = LN(xin + add) * g + b  (also emits bf16 copy for next MFMA GEMM)
__global__ __launch_bounds__(64) void ln_kernel(
    const float* __restrict__ xin, const float* __restrict__ add,
    const float* __restrict__ g, const float* __restrict__ bt,
    float* __restrict__ xout, ushort* __restrict__ xbout)
{
    int row = blockIdx.x, t = threadIdx.x;
    float4 xv = *(const float4*)&xin[(size_t)row * E_ + t * 4];
    float4 av = *(const float4*)&add[(size_t)row * E_ + t * 4];
    xv.x += av.x; xv.y += av.y; xv.z += av.z; xv.w += av.w;
    float sum = xv.x + xv.y + xv.z + xv.w;
    #pragma unroll
    for (int off = 32; off; off >>= 1) sum += __shfl_xor(sum, off, 64);
    float mean = sum * (1.f / 256.f);
    float dx = xv.x - mean, dy = xv.y - mean, dz = xv.z - mean, dw = xv.w - mean;
    float sq = dx * dx + dy * dy + dz * dz + dw * dw;
    #pragma unroll
    for (int off = 32; off; off >>= 1) sq += __shfl_xor(sq, off, 64);
    float rstd = rsqrtf(sq * (1.f / 256.f) + 1e-12f);
    float4 gv = *(const float4*)&g[t * 4];
    float4 bv = *(const float4*)&bt[t * 4];
    float4 ov;
    ov.x = dx * rstd * gv.x + bv.x;
    ov.y = dy * rstd * gv.y + bv.y;
    ov.z = dz * rstd * gv.z + bv.z;
    ov.w = dw * rstd * gv.w + bv.w;
    *(float4*)&xout[(size_t)row * E_ + t * 4] = ov;
    ushort4 hb;
    hb.x = f2b(ov.x); hb.y = f2b(ov.y); hb.z = f2b(ov.z); hb.w = f2b(ov.w);
    *(ushort4*)&xbout[(size_t)row * E_ + t * 4] = hb;
}

// ---------------------------------------------------------------------------
extern "C" void kernel_launch(void* const* d_in, const int* in_sizes, int n_in,
                              void* d_out, int out_size, void* d_ws, size_t ws_size,
                              hipStream_t stream) {
    const float* node_feat = (const float*)d_in[0];
    const int*   node_opc  = (const int*)d_in[1];
    const int*   dist_mat  = (const int*)d_in[2];
    const float* W_op      = (const float*)d_in[3];
    const float* W_feat    = (const float*)d_in[4];
    const float* b_feat    = (const float*)d_in[5];
    const float* W_mlp1    = (const float*)d_in[6];
    const float* b_mlp1    = (const float*)d_in[7];
    const float* W_mlp2    = (const float*)d_in[8];
    const float* b_mlp2    = (const float*)d_in[9];
    const float* cls       = (const float*)d_in[10];
    const float* dist_tab  = (const float*)d_in[11];
    const float* Wq = (const float*)d_in[12]; const float* bq = (const float*)d_in[13];
    const float* Wk = (const float*)d_in[14]; const float* bk = (const float*)d_in[15];
    const float* Wv = (const float*)d_in[16]; const float* bv = (const float*)d_in[17];
    const float* Wo = (const float*)d_in[18]; const float* bo = (const float*)d_in[19];
    const float* ln1g = (const float*)d_in[20]; const float* ln1b = (const float*)d_in[21];
    const float* Wf1 = (const float*)d_in[22]; const float* bf1 = (const float*)d_in[23];
    const float* Wf2 = (const float*)d_in[24]; const float* bf2 = (const float*)d_in[25];
    const float* ln2g = (const float*)d_in[26]; const float* ln2b = (const float*)d_in[27];

    float* out = (float*)d_out;
    float* ws  = (float*)d_ws;
    // workspace layout, float units (total ~120.6 MB)
    float* biasb = ws;                        // 8388608
    float* x     = biasb + 8388608;           // 2097152
    float* qb    = x  + 2097152;              // 2097152
    float* kb    = qb + 2097152;              // 2097152
    float* vb    = kb + 2097152;              // 2097152
    float* big   = vb + 2097152;              // 8388608 (opart | ffnb | hcat)
    float* mlbuf = big + 8388608;             // 524288
    ushort* xb   = (ushort*)(mlbuf + 524288); // 2097152 ushort
    ushort* cbb  = xb + 2097152;              // 2097152 ushort
    ushort* wts  = cbb + 2097152;             // 4718592 ushort
    float*  opart = big;
    float*  hcat  = big;                      // pre-layer only (8192*512 fits)
    ushort* ffnb  = (ushort*)big;             // FFN intermediate bf16 (fits)
    float* h1 = qb;  // pre-layer alias
    float* h2 = kb;  // pre-layer alias

    // bf16 transposed weights
    ushort* wqt  = wts;                 // 6*256*256
    ushort* wkt  = wqt + 393216;
    ushort* wvt  = wkt + 393216;
    ushort* wot  = wvt + 393216;
    ushort* wf1t = wot + 393216;        // 6*1024*256  (orig [256][1024] -> [1024][256])
    ushort* wf2t = wf1t + 1572864;      // 6*256*1024  (orig [1024][256] -> [256][1024])

    // --- one-time-per-launch weight conversion ---
    wconv_t<<<1536, 256, 0, stream>>>(Wq, wqt, 256, 256);
    wconv_t<<<1536, 256, 0, stream>>>(Wk, wkt, 256, 256);
    wconv_t<<<1536, 256, 0, stream>>>(Wv, wvt, 256, 256);
    wconv_t<<<1536, 256, 0, stream>>>(Wo, wot, 256, 256);
    wconv_t<<<6144, 256, 0, stream>>>(Wf1, wf1t, 256, 1024);
    wconv_t<<<6144, 256, 0, stream>>>(Wf2, wf2t, 1024, 256);

    bias_kernel<<<32768, 256, 0, stream>>>(dist_mat, dist_tab, biasb);
    opgather_kernel<<<8184, 256, 0, stream>>>(node_opc, W_op, hcat);
    gemm_kernel<0><<<dim3(128, 4), 256, 0, stream>>>(node_feat, 140, W_feat, 256, b_feat,
                                                     hcat + 256, 512, 8184, 256, 140);
    gemm_kernel<1><<<dim3(128, 4), 256, 0, stream>>>(hcat, 512, W_mlp1, 256, b_mlp1,
                                                     h1, 256, 8184, 256, 512);
    gemm_kernel<0><<<dim3(128, 4), 256, 0, stream>>>(h1, 256, W_mlp2, 256, b_mlp2,
                                                     h2, 256, 8184, 256, 256);
    assemble_kernel<<<8192, 256, 0, stream>>>(cls, h2, x, xb);

    for (int l = 0; l < L_; l++) {
        const ushort* wqt_l = wqt + l * 65536;  const float* bq_l = bq + l * 256;
        const ushort* wkt_l = wkt + l * 65536;  const float* bk_l = bk + l * 256;
        const ushort* wvt_l = wvt + l * 65536;  const float* bv_l = bv + l * 256;
        const ushort* wot_l = wot + l * 65536;  const float* bo_l = bo + l * 256;
        const ushort* wf1t_l = wf1t + l * 262144; const float* bf1_l = bf1 + l * 1024;
        const ushort* wf2t_l = wf2t + l * 262144; const float* bf2_l = bf2 + l * 256;

        mgemm<0><<<dim3(128, 4), 256, 0, stream>>>(xb, wqt_l, bq_l, qb, 8192, 256, 256);
        mgemm<0><<<dim3(128, 4), 256, 0, stream>>>(xb, wkt_l, bk_l, kb, 8192, 256, 256);
        mgemm<0><<<dim3(128, 4), 256, 0, stream>>>(xb, wvt_l, bv_l, vb, 8192, 256, 256);
        attn_kernel<<<2048, 64, 0, stream>>>(qb, kb, vb, biasb, opart, mlbuf);
        attn_merge<<<256, 256, 0, stream>>>(opart, mlbuf, cbb);
        mgemm<0><<<dim3(128, 4), 256, 0, stream>>>(cbb, wot_l, bo_l, qb, 8192, 256, 256);
        ln_kernel<<<8192, 64, 0, stream>>>(x, qb, ln1g + l * 256, ln1b + l * 256, x, xb);
        mgemm<1><<<dim3(128, 16), 256, 0, stream>>>(xb, wf1t_l, bf1_l, ffnb, 8192, 1024, 256);
        mgemm<0><<<dim3(128, 4), 256, 0, stream>>>((const ushort*)ffnb, wf2t_l, bf2_l, qb,
                                                   8192, 256, 1024);
        ln_kernel<<<8192, 64, 0, stream>>>(x, qb, ln2g + l * 256, ln2b + l * 256,
                                           (l == L_ - 1) ? out : x, xb);
    }
}

// Round 7
// 978.578 us; speedup vs baseline: 5.0899x; 1.8331x over previous
//
#include <hip/hip_runtime.h>
#include <math.h>

#define B_ 8
#define N_ 1023
#define S_ 1024
#define E_ 256
#define H_ 8
#define D_ 32
#define L_ 6
#define F_ 1024
#define LDK 72   // LDS leading dim (k) for Vt and P tiles: 16B-aligned rows, bank-spread

typedef __attribute__((ext_vector_type(8))) short bf16x8;
typedef __attribute__((ext_vector_type(4))) float f32x4;

__device__ __forceinline__ ushort f2b(float x) {
    unsigned u = __float_as_uint(x);
    return (ushort)((u + 0x7fffu + ((u >> 16) & 1u)) >> 16);
}

// ---------------------------------------------------------------------------
// dist bias: bias[b,q,k] = table[min(d,31)] (d==-1 -> idx 32 -> JAX clamps to 31)
__global__ __launch_bounds__(256) void bias_kernel(const int* __restrict__ dm,
                                                   const float* __restrict__ table,
                                                   float* __restrict__ out) {
    int idx = blockIdx.x * 256 + threadIdx.x;          // exactly B_*S_*S_
    int d = dm[idx];
    int ii = ((unsigned)d > 30u) ? 31 : d;
    out[idx] = table[ii];
}

// op embedding gather into left half of hcat (ld 512)
__global__ __launch_bounds__(256) void opgather_kernel(const int* __restrict__ opc,
                                                       const float* __restrict__ W_op,
                                                       float* __restrict__ hcat) {
    int idx = blockIdx.x * 256 + threadIdx.x;          // 8184*256
    int row = idx >> 8, c = idx & 255;
    hcat[(size_t)row * 512 + c] = W_op[opc[row] * 256 + c];
}

// x[b,0,:]=cls ; x[b,1+n,:]=h[b*N+n,:]   (also emits bf16 copy)
__global__ __launch_bounds__(256) void assemble_kernel(const float* __restrict__ cls,
                                                       const float* __restrict__ h,
                                                       float* __restrict__ x,
                                                       ushort* __restrict__ xb) {
    int idx = blockIdx.x * 256 + threadIdx.x;          // B_*S_*E_
    int c = idx & 255;
    int s = (idx >> 8) & 1023;
    int b = idx >> 18;
    float v = (s == 0) ? cls[c] : h[((size_t)(b * N_ + s - 1)) * 256 + c];
    x[idx] = v;
    xb[idx] = f2b(v);
}

// ---------------------------------------------------------------------------
// Weight convert + transpose: out[l][n][k] = bf16(in[l][k][n]).
__global__ __launch_bounds__(256) void wconv_t(const float* __restrict__ in,
                                               ushort* __restrict__ out,
                                               int K, int Nn) {
    int idx = blockIdx.x * 256 + threadIdx.x;
    int per = K * Nn;
    int lw = idx / per, rem = idx - lw * per;
    int n = rem / K, k = rem - n * K;
    out[idx] = f2b(in[(size_t)lw * per + (size_t)k * Nn + n]);
}

// ---------------------------------------------------------------------------
// MFMA bf16 GEMM: C[M,N] = epi(A[M,K]_bf16 @ B[K,N] + bias[N])
// B supplied TRANSPOSED as Bt[N][K] bf16. BM=BN=64, BK=32, 4 waves (2x2).
// EPI 0: fp32 out. EPI 1: exact GELU, bf16 out. EPI 2: plain bf16 out.
template<int EPI>
__global__ __launch_bounds__(256) void mgemm(
    const ushort* __restrict__ A, const ushort* __restrict__ Bt,
    const float* __restrict__ bias, void* __restrict__ C,
    int M, int Nn, int K)
{
    __shared__ ushort As[64 * 32];
    __shared__ ushort Bs[64 * 32];
    const int t = threadIdx.x;
    const int m0 = blockIdx.x * 64, n0 = blockIdx.y * 64;
    const int l = t & 63, w = t >> 6;
    const int wr = (w >> 1) * 32, wc = (w & 1) * 32;
    const int sr = t >> 2, sc = (t & 3) * 8;   // staging: row, 8-elem chunk
    const int l15 = l & 15, lk = (l >> 4) * 8;

    f32x4 zero = {0.f, 0.f, 0.f, 0.f};
    f32x4 acc00 = zero, acc01 = zero, acc10 = zero, acc11 = zero;

    const ushort* ap = A + (size_t)(m0 + sr) * K + sc;
    const ushort* bp = Bt + (size_t)(n0 + sr) * K + sc;
    bf16x8 ra = *(const bf16x8*)ap;
    bf16x8 rb = *(const bf16x8*)bp;

    for (int kt = 0; kt < K; kt += 32) {
        *(bf16x8*)&As[sr * 32 + sc] = ra;
        *(bf16x8*)&Bs[sr * 32 + sc] = rb;
        __syncthreads();
        if (kt + 32 < K) {                       // prefetch next tile into regs
            ra = *(const bf16x8*)(ap + kt + 32);
            rb = *(const bf16x8*)(bp + kt + 32);
        }
        bf16x8 a0 = *(bf16x8*)&As[(wr + l15) * 32 + lk];
        bf16x8 a1 = *(bf16x8*)&As[(wr + 16 + l15) * 32 + lk];
        bf16x8 b0 = *(bf16x8*)&Bs[(wc + l15) * 32 + lk];
        bf16x8 b1 = *(bf16x8*)&Bs[(wc + 16 + l15) * 32 + lk];
        acc00 = __builtin_amdgcn_mfma_f32_16x16x32_bf16(a0, b0, acc00, 0, 0, 0);
        acc01 = __builtin_amdgcn_mfma_f32_16x16x32_bf16(a0, b1, acc01, 0, 0, 0);
        acc10 = __builtin_amdgcn_mfma_f32_16x16x32_bf16(a1, b0, acc10, 0, 0, 0);
        acc11 = __builtin_amdgcn_mfma_f32_16x16x32_bf16(a1, b1, acc11, 0, 0, 0);
        __syncthreads();
    }
    // D mapping: col = lane&15, row = (lane>>4)*4 + r
    const int cn = n0 + wc + l15;
    const int rbase = m0 + wr + (l >> 4) * 4;
    float bv0 = bias[cn], bv1 = bias[cn + 16];
    #pragma unroll
    for (int i = 0; i < 2; i++) {
        f32x4 aj0 = i ? acc10 : acc00;
        f32x4 aj1 = i ? acc11 : acc01;
        #pragma unroll
        for (int r = 0; r < 4; r++) {
            int row = rbase + i * 16 + r;
            float v0 = aj0[r] + bv0;
            float v1 = aj1[r] + bv1;
            if (EPI == 0) {
                ((float*)C)[(size_t)row * Nn + cn] = v0;
                ((float*)C)[(size_t)row * Nn + cn + 16] = v1;
            } else {
                if (EPI == 1) {
                    v0 = 0.5f * v0 * (1.f + erff(v0 * 0.70710678118654752f));
                    v1 = 0.5f * v1 * (1.f + erff(v1 * 0.70710678118654752f));
                }
                ((ushort*)C)[(size_t)row * Nn + cn] = f2b(v0);
                ((ushort*)C)[(size_t)row * Nn + cn + 16] = f2b(v1);
            }
        }
    }
}

// ---------------------------------------------------------------------------
// Tiled fp32 GEMM (guarded) — pre-layer only (M=8184, K=140/512/256).
template<int EPI>
__global__ __launch_bounds__(256) void gemm_kernel(
    const float* __restrict__ A, int lda,
    const float* __restrict__ Bm, int ldb,
    const float* __restrict__ bias,
    float* __restrict__ C, int ldc,
    int M, int Nn, int K)
{
    __shared__ float As[16][68];
    __shared__ float Bs[16][68];
    const int t = threadIdx.x;
    const int m0 = blockIdx.x * 64, n0 = blockIdx.y * 64;
    const int tx = t & 15, ty = t >> 4;
    const int tm = ty * 4, tn = tx * 4;
    float acc[4][4] = {};
    const int am = t >> 2, ak = (t & 3) * 4;
    const int bkr = t >> 4, bn4 = (t & 15) * 4;
    const int nt = (K + 15) >> 4;
    for (int kt = 0; kt < nt; kt++) {
        int k0 = kt * 16;
        #pragma unroll
        for (int j = 0; j < 4; j++) {
            int kk = k0 + ak + j;
            float v = 0.f;
            if (m0 + am < M && kk < K) v = A[(size_t)(m0 + am) * lda + kk];
            As[ak + j][am] = v;
        }
        {
            float4 v = {0.f, 0.f, 0.f, 0.f};
            if (k0 + bkr < K) v = *(const float4*)&Bm[(size_t)(k0 + bkr) * ldb + n0 + bn4];
            *(float4*)&Bs[bkr][bn4] = v;
        }
        __syncthreads();
        #pragma unroll
        for (int kk = 0; kk < 16; kk++) {
            float4 a = *(const float4*)&As[kk][tm];
            float4 b = *(const float4*)&Bs[kk][tn];
            float av[4] = {a.x, a.y, a.z, a.w};
            float bw[4] = {b.x, b.y, b.z, b.w};
            #pragma unroll
            for (int i = 0; i < 4; i++)
                #pragma unroll
                for (int j = 0; j < 4; j++)
                    acc[i][j] = fmaf(av[i], bw[j], acc[i][j]);
        }
        __syncthreads();
    }
    #pragma unroll
    for (int j = 0; j < 4; j++) {
        float bv = bias ? bias[n0 + tn + j] : 0.f;
        #pragma unroll
        for (int i = 0; i < 4; i++) {
            int m = m0 + tm + i;
            if (m < M) {
                float v = acc[i][j] + bv;
                if (EPI == 1) v = 0.5f * v * (1.f + erff(v * 0.70710678118654752f));
                C[(size_t)m * ldc + n0 + tn + j] = v;
            }
        }
    }
}

// ---------------------------------------------------------------------------
// MFMA flash attention. Block = 256 thr (4 waves), each wave owns 32 q-rows;
// block covers 128 q-rows of one (b,h). K-tiles of 64 keys.
// S^T = mfma(K_frag, Q_frag)  [k x q tiles; K frags loaded direct from global]
// softmax online in S^T layout (per-q reduce = in-reg + shfl_xor 16,32)
// P -> wave-private LDS [q][k] bf16 ; V -> cooperative LDS transpose Vt[d][k]
// ctx^T += mfma(Vt_frag, P_frag). Epilogue: /l, bf16 scatter store.
__global__ __launch_bounds__(256, 2) void attn_mfma(
    const ushort* __restrict__ Qm, const ushort* __restrict__ Km,
    const ushort* __restrict__ Vm, const float* __restrict__ bias,
    ushort* __restrict__ ctxb)
{
    __shared__ ushort Vt[32 * LDK];            // V^T tile: [d][k], 64 keys
    __shared__ ushort Pl[4][32 * LDK];         // per-wave P: [q][k] bf16
    const int t = threadIdx.x;
    const int bid = blockIdx.x;                // 512 = b(3)|h(3)|qt(3)
    const int qt = bid & 7;
    const int h  = (bid >> 3) & 7;
    const int b  = bid >> 6;
    const int wv = t >> 6, l = t & 63;
    const int g = l >> 4, l15 = l & 15;
    const float scale = 0.17677669529663687f;

    const int q0 = qt * 128 + wv * 32;         // wave's first q row
    const size_t base = (size_t)(b * S_) * E_ + h * D_;

    // Q fragments: lane holds Q[q0 + 16*qs + l15][8g .. 8g+7]
    bf16x8 qf[2];
    #pragma unroll
    for (int qs = 0; qs < 2; qs++)
        qf[qs] = *(const bf16x8*)&Qm[base + (size_t)(q0 + qs * 16 + l15) * E_ + g * 8];

    f32x4 ctx[2][2] = {};                      // [dsub][qsub] ctx^T tiles
    float mrun[2] = {-3e38f, -3e38f}, lrun[2] = {0.f, 0.f};

    // V staging map: thread handles k-pair pr, d-quad dq
    const int pr = t >> 3, dq = (t & 7) * 4;
    const ushort* vrow0 = &Vm[base + (size_t)(2 * pr) * E_ + dq];
    const float* bp = bias + ((size_t)b * S_ + q0) * S_;
    ushort* pw = &Pl[wv][0];

    for (int kt = 0; kt < S_; kt += 64) {
        // issue V loads early; consumed after QK/softmax (latency hidden)
        ushort4 v0 = *(const ushort4*)&vrow0[(size_t)kt * E_];
        ushort4 v1 = *(const ushort4*)&vrow0[(size_t)kt * E_ + E_];

        // ---- QK^T -> S^T[k][q] ----
        f32x4 s[4][2];
        #pragma unroll
        for (int ks = 0; ks < 4; ks++) {
            bf16x8 kf = *(const bf16x8*)&Km[base + (size_t)(kt + ks * 16 + l15) * E_ + g * 8];
            #pragma unroll
            for (int qs = 0; qs < 2; qs++) {
                f32x4 z = {0.f, 0.f, 0.f, 0.f};
                s[ks][qs] = __builtin_amdgcn_mfma_f32_16x16x32_bf16(kf, qf[qs], z, 0, 0, 0);
            }
        }
        // ---- scale + bias (bias[q][k]: lane q=l15+16qs, k=kt+16ks+4g+r) ----
        #pragma unroll
        for (int qs = 0; qs < 2; qs++) {
            const float* bq_ = bp + (size_t)(qs * 16 + l15) * S_ + kt + g * 4;
            #pragma unroll
            for (int ks = 0; ks < 4; ks++) {
                float4 bb = *(const float4*)&bq_[ks * 16];
                s[ks][qs][0] = fmaf(s[ks][qs][0], scale, bb.x);
                s[ks][qs][1] = fmaf(s[ks][qs][1], scale, bb.y);
                s[ks][qs][2] = fmaf(s[ks][qs][2], scale, bb.z);
                s[ks][qs][3] = fmaf(s[ks][qs][3], scale, bb.w);
            }
        }
        // ---- online softmax per qsub ----
        #pragma unroll
        for (int qs = 0; qs < 2; qs++) {
            float mx = s[0][qs][0];
            #pragma unroll
            for (int ks = 0; ks < 4; ks++)
                #pragma unroll
                for (int r = 0; r < 4; r++) mx = fmaxf(mx, s[ks][qs][r]);
            mx = fmaxf(mx, __shfl_xor(mx, 16, 64));
            mx = fmaxf(mx, __shfl_xor(mx, 32, 64));
            float mn = fmaxf(mrun[qs], mx);
            float corr = __expf(mrun[qs] - mn);
            mrun[qs] = mn;
            float ps = 0.f;
            #pragma unroll
            for (int ks = 0; ks < 4; ks++)
                #pragma unroll
                for (int r = 0; r < 4; r++) {
                    float e = __expf(s[ks][qs][r] - mn);
                    s[ks][qs][r] = e; ps += e;
                }
            ps += __shfl_xor(ps, 16, 64);
            ps += __shfl_xor(ps, 32, 64);
            lrun[qs] = lrun[qs] * corr + ps;
            #pragma unroll
            for (int ds = 0; ds < 2; ds++) {
                ctx[ds][qs][0] *= corr; ctx[ds][qs][1] *= corr;
                ctx[ds][qs][2] *= corr; ctx[ds][qs][3] *= corr;
            }
        }
        // ---- P -> LDS [q][k] bf16 (wave-private, no barrier needed) ----
        #pragma unroll
        for (int qs = 0; qs < 2; qs++)
            #pragma unroll
            for (int ks = 0; ks < 4; ks++) {
                uint2 pk;
                pk.x = (uint)f2b(s[ks][qs][0]) | ((uint)f2b(s[ks][qs][1]) << 16);
                pk.y = (uint)f2b(s[ks][qs][2]) | ((uint)f2b(s[ks][qs][3]) << 16);
                *(uint2*)&pw[(qs * 16 + l15) * LDK + ks * 16 + g * 4] = pk;
            }
        // ---- V transpose into LDS (cooperative) ----
        __syncthreads();     // prior tile's PV reads complete
        {
            uint p0 = (uint)v0.x | ((uint)v1.x << 16);
            uint p1 = (uint)v0.y | ((uint)v1.y << 16);
            uint p2 = (uint)v0.z | ((uint)v1.z << 16);
            uint p3 = (uint)v0.w | ((uint)v1.w << 16);
            *(uint*)&Vt[(dq + 0) * LDK + 2 * pr] = p0;
            *(uint*)&Vt[(dq + 1) * LDK + 2 * pr] = p1;
            *(uint*)&Vt[(dq + 2) * LDK + 2 * pr] = p2;
            *(uint*)&Vt[(dq + 3) * LDK + 2 * pr] = p3;
        }
        __syncthreads();     // Vt ready
        // ---- PV: ctx^T += V^T · P^T ----
        #pragma unroll
        for (int kc = 0; kc < 2; kc++) {
            bf16x8 pf[2], vf[2];
            #pragma unroll
            for (int qs = 0; qs < 2; qs++)
                pf[qs] = *(bf16x8*)&pw[(qs * 16 + l15) * LDK + kc * 32 + g * 8];
            #pragma unroll
            for (int ds = 0; ds < 2; ds++)
                vf[ds] = *(bf16x8*)&Vt[(ds * 16 + l15) * LDK + kc * 32 + g * 8];
            #pragma unroll
            for (int ds = 0; ds < 2; ds++)
                #pragma unroll
                for (int qs = 0; qs < 2; qs++)
                    ctx[ds][qs] = __builtin_amdgcn_mfma_f32_16x16x32_bf16(
                        vf[ds], pf[qs], ctx[ds][qs], 0, 0, 0);
        }
    }
    // ---- epilogue: ctx^T / l -> bf16 scatter (col q = l15, row d) ----
    #pragma unroll
    for (int qs = 0; qs < 2; qs++) {
        float inv = 1.f / lrun[qs];
        ushort* op = &ctxb[base + (size_t)(q0 + qs * 16 + l15) * E_];
        #pragma unroll
        for (int ds = 0; ds < 2; ds++)
            #pragma unroll
            for (int r = 0; r < 4; r++)
                op[ds * 16 + g * 4 + r] = f2b(ctx[ds][qs][r] * inv);
    }
}

// ---------------------------------------------------------------------------
// xout = LN(xin + add) * g + b  (also emits bf16 copy for next MFMA GEMM)
__global__ __launch_bounds__(64) void ln_kernel(
    const float* __restrict__ xin, const float* __restrict__ add,
    const float* __restrict__ g, const float* __restrict__ bt,
    float* __restrict__ xout, ushort* __restrict__ xbout)
{
    int row = blockIdx.x, t = threadIdx.x;
    float4 xv = *(const float4*)&xin[(size_t)row * E_ + t * 4];
    float4 av = *(const float4*)&add[(size_t)row * E_ + t * 4];
    xv.x += av.x; xv.y += av.y; xv.z += av.z; xv.w += av.w;
    float sum = xv.x + xv.y + xv.z + xv.w;
    #pragma unroll
    for (int off = 32; off; off >>= 1) sum += __shfl_xor(sum, off, 64);
    float mean = sum * (1.f / 256.f);
    float dx = xv.x - mean, dy = xv.y - mean, dz = xv.z - mean, dw = xv.w - mean;
    float sq = dx * dx + dy * dy + dz * dz + dw * dw;
    #pragma unroll
    for (int off = 32; off; off >>= 1) sq += __shfl_xor(sq, off, 64);
    float rstd = rsqrtf(sq * (1.f / 256.f) + 1e-12f);
    float4 gv = *(const float4*)&g[t * 4];
    float4 bv = *(const float4*)&bt[t * 4];
    float4 ov;
    ov.x = dx * rstd * gv.x + bv.x;
    ov.y = dy * rstd * gv.y + bv.y;
    ov.z = dz * rstd * gv.z + bv.z;
    ov.w = dw * rstd * gv.w + bv.w;
    *(float4*)&xout[(size_t)row * E_ + t * 4] = ov;
    ushort4 hb;
    hb.x = f2b(ov.x); hb.y = f2b(ov.y); hb.z = f2b(ov.z); hb.w = f2b(ov.w);
    *(ushort4*)&xbout[(size_t)row * E_ + t * 4] = hb;
}

// ---------------------------------------------------------------------------
extern "C" void kernel_launch(void* const* d_in, const int* in_sizes, int n_in,
                              void* d_out, int out_size, void* d_ws, size_t ws_size,
                              hipStream_t stream) {
    const float* node_feat = (const float*)d_in[0];
    const int*   node_opc  = (const int*)d_in[1];
    const int*   dist_mat  = (const int*)d_in[2];
    const float* W_op      = (const float*)d_in[3];
    const float* W_feat    = (const float*)d_in[4];
    const float* b_feat    = (const float*)d_in[5];
    const float* W_mlp1    = (const float*)d_in[6];
    const float* b_mlp1    = (const float*)d_in[7];
    const float* W_mlp2    = (const float*)d_in[8];
    const float* b_mlp2    = (const float*)d_in[9];
    const float* cls       = (const float*)d_in[10];
    const float* dist_tab  = (const float*)d_in[11];
    const float* Wq = (const float*)d_in[12]; const float* bq = (const float*)d_in[13];
    const float* Wk = (const float*)d_in[14]; const float* bk = (const float*)d_in[15];
    const float* Wv = (const float*)d_in[16]; const float* bv = (const float*)d_in[17];
    const float* Wo = (const float*)d_in[18]; const float* bo = (const float*)d_in[19];
    const float* ln1g = (const float*)d_in[20]; const float* ln1b = (const float*)d_in[21];
    const float* Wf1 = (const float*)d_in[22]; const float* bf1 = (const float*)d_in[23];
    const float* Wf2 = (const float*)d_in[24]; const float* bf2 = (const float*)d_in[25];
    const float* ln2g = (const float*)d_in[26]; const float* ln2b = (const float*)d_in[27];

    float* out = (float*)d_out;
    float* ws  = (float*)d_ws;
    // workspace layout, float units
    float* biasb = ws;                        // 8388608
    float* x     = biasb + 8388608;           // 2097152
    float* qb    = x  + 2097152;              // 2097152
    float* kb    = qb + 2097152;              // 2097152
    float* vb    = kb + 2097152;              // 2097152
    float* big   = vb + 2097152;              // 8388608 (ffnb | hcat)
    float* mlbuf = big + 8388608;             // 524288 (spare)
    ushort* xb   = (ushort*)(mlbuf + 524288); // 2097152 ushort
    ushort* cbb  = xb + 2097152;              // 2097152 ushort
    ushort* wts  = cbb + 2097152;             // 4718592 ushort
    float*  hcat  = big;                      // pre-layer only
    ushort* ffnb  = (ushort*)big;             // FFN intermediate bf16
    float* h1 = qb;  // pre-layer alias
    float* h2 = kb;  // pre-layer alias
    ushort* qbb = (ushort*)qb;                // bf16 q/k/v (half of fp32 regions)
    ushort* kbb = (ushort*)kb;
    ushort* vbb = (ushort*)vb;

    // bf16 transposed weights
    ushort* wqt  = wts;                 // 6*256*256
    ushort* wkt  = wqt + 393216;
    ushort* wvt  = wkt + 393216;
    ushort* wot  = wvt + 393216;
    ushort* wf1t = wot + 393216;        // 6*1024*256
    ushort* wf2t = wf1t + 1572864;      // 6*256*1024

    wconv_t<<<1536, 256, 0, stream>>>(Wq, wqt, 256, 256);
    wconv_t<<<1536, 256, 0, stream>>>(Wk, wkt, 256, 256);
    wconv_t<<<1536, 256, 0, stream>>>(Wv, wvt, 256, 256);
    wconv_t<<<1536, 256, 0, stream>>>(Wo, wot, 256, 256);
    wconv_t<<<6144, 256, 0, stream>>>(Wf1, wf1t, 256, 1024);
    wconv_t<<<6144, 256, 0, stream>>>(Wf2, wf2t, 1024, 256);

    bias_kernel<<<32768, 256, 0, stream>>>(dist_mat, dist_tab, biasb);
    opgather_kernel<<<8184, 256, 0, stream>>>(node_opc, W_op, hcat);
    gemm_kernel<0><<<dim3(128, 4), 256, 0, stream>>>(node_feat, 140, W_feat, 256, b_feat,
                                                     hcat + 256, 512, 8184, 256, 140);
    gemm_kernel<1><<<dim3(128, 4), 256, 0, stream>>>(hcat, 512, W_mlp1, 256, b_mlp1,
                                                     h1, 256, 8184, 256, 512);
    gemm_kernel<0><<<dim3(128, 4), 256, 0, stream>>>(h1, 256, W_mlp2, 256, b_mlp2,
                                                     h2, 256, 8184, 256, 256);
    assemble_kernel<<<8192, 256, 0, stream>>>(cls, h2, x, xb);

    for (int l = 0; l < L_; l++) {
        const ushort* wqt_l = wqt + l * 65536;  const float* bq_l = bq + l * 256;
        const ushort* wkt_l = wkt + l * 65536;  const float* bk_l = bk + l * 256;
        const ushort* wvt_l = wvt + l * 65536;  const float* bv_l = bv + l * 256;
        const ushort* wot_l = wot + l * 65536;  const float* bo_l = bo + l * 256;
        const ushort* wf1t_l = wf1t + l * 262144; const float* bf1_l = bf1 + l * 1024;
        const ushort* wf2t_l = wf2t + l * 262144; const float* bf2_l = bf2 + l * 256;

        mgemm<2><<<dim3(128, 4), 256, 0, stream>>>(xb, wqt_l, bq_l, qbb, 8192, 256, 256);
        mgemm<2><<<dim3(128, 4), 256, 0, stream>>>(xb, wkt_l, bk_l, kbb, 8192, 256, 256);
        mgemm<2><<<dim3(128, 4), 256, 0, stream>>>(xb, wvt_l, bv_l, vbb, 8192, 256, 256);
        attn_mfma<<<512, 256, 0, stream>>>(qbb, kbb, vbb, biasb, cbb);
        mgemm<0><<<dim3(128, 4), 256, 0, stream>>>(cbb, wot_l, bo_l, qb, 8192, 256, 256);
        ln_kernel<<<8192, 64, 0, stream>>>(x, qb, ln1g + l * 256, ln1b + l * 256, x, xb);
        mgemm<1><<<dim3(128, 16), 256, 0, stream>>>(xb, wf1t_l, bf1_l, ffnb, 8192, 1024, 256);
        mgemm<0><<<dim3(128, 4), 256, 0, stream>>>((const ushort*)ffnb, wf2t_l, bf2_l, qb,
                                                   8192, 256, 1024);
        ln_kernel<<<8192, 64, 0, stream>>>(x, qb, ln2g + l * 256, ln2b + l * 256,
                                           (l == L_ - 1) ? out : x, xb);
    }
}

// Round 8
// 949.267 us; speedup vs baseline: 5.2470x; 1.0309x over previous
//
#include <hip/hip_runtime.h>
#include <math.h>

#define B_ 8
#define N_ 1023
#define S_ 1024
#define E_ 256
#define H_ 8
#define D_ 32
#define L_ 6
#define F_ 1024
#define LDK 72   // attn LDS leading dim (k) for Vt/P tiles

typedef __attribute__((ext_vector_type(8))) short bf16x8;
typedef __attribute__((ext_vector_type(4))) float f32x4;

__device__ __forceinline__ ushort f2b(float x) {
    unsigned u = __float_as_uint(x);
    return (ushort)((u + 0x7fffu + ((u >> 16) & 1u)) >> 16);
}

// ---------------------------------------------------------------------------
// dist bias: bias[b,q,k] = table[min(d,31)]
__global__ __launch_bounds__(256) void bias_kernel(const int* __restrict__ dm,
                                                   const float* __restrict__ table,
                                                   float* __restrict__ out) {
    int idx = blockIdx.x * 256 + threadIdx.x;          // exactly B_*S_*S_
    int d = dm[idx];
    int ii = ((unsigned)d > 30u) ? 31 : d;
    out[idx] = table[ii];
}

// node_feat -> bf16, zero-padded to [8192][160]
__global__ __launch_bounds__(256) void nfconv(const float* __restrict__ nf,
                                              ushort* __restrict__ out) {
    int idx = blockIdx.x * 256 + threadIdx.x;          // 8192*160
    int r = idx / 160, k = idx - r * 160;
    float v = (r < 8184 && k < 140) ? nf[r * 140 + k] : 0.f;
    out[idx] = f2b(v);
}

// op embedding gather (bf16) into left half of hcatb (ld 512); rows>=8184 zero
__global__ __launch_bounds__(256) void opgather_kernel(const int* __restrict__ opc,
                                                       const float* __restrict__ W_op,
                                                       ushort* __restrict__ hcatb) {
    int idx = blockIdx.x * 256 + threadIdx.x;          // 8192*256
    int row = idx >> 8, c = idx & 255;
    float v = (row < 8184) ? W_op[opc[row] * 256 + c] : 0.f;
    hcatb[(size_t)row * 512 + c] = f2b(v);
}

// x[b,0,:]=cls ; x[b,1+n,:]=h[b*N+n,:]   (also emits bf16 copy)
__global__ __launch_bounds__(256) void assemble_kernel(const float* __restrict__ cls,
                                                       const float* __restrict__ h,
                                                       float* __restrict__ x,
                                                       ushort* __restrict__ xb) {
    int idx = blockIdx.x * 256 + threadIdx.x;          // B_*S_*E_
    int c = idx & 255;
    int s = (idx >> 8) & 1023;
    int b = idx >> 18;
    float v = (s == 0) ? cls[c] : h[((size_t)(b * N_ + s - 1)) * 256 + c];
    x[idx] = v;
    xb[idx] = f2b(v);
}

// ---------------------------------------------------------------------------
// Weight convert + transpose + K-pad: out[l][n][kp] = kp<K ? bf16(in[l][kp][n]) : 0
__global__ __launch_bounds__(256) void wconv_t(const float* __restrict__ in,
                                               ushort* __restrict__ out,
                                               int K, int Kp, int Nn) {
    int idx = blockIdx.x * 256 + threadIdx.x;
    int per = Kp * Nn;
    int lw = idx / per, rem = idx - lw * per;
    int n = rem / Kp, k = rem - n * Kp;
    out[idx] = (k < K) ? f2b(in[(size_t)lw * K * Nn + (size_t)k * Nn + n]) : (ushort)0;
}

// ---------------------------------------------------------------------------
// MFMA bf16 GEMM v2: C[M,N] = epi(A[M,K]_bf16 @ B[K,N] + bias[N]); Bt[N][K].
// BM=128, BN in {64,128}, BK=32, 256 thr = 4 waves (2x2); wave owns
// 64 x (BN/2) via 4 x NB frags of v_mfma_f32_16x16x32_bf16.
// LDS pitch 36 (72B rows): 16 consecutive-row lanes -> 16 distinct banks.
// EPI 0: fp32 out. EPI 1: exact GELU, bf16 out. EPI 2: plain bf16 out.
template<int EPI, int BN>
__global__ __launch_bounds__(256) void mgemm2(
    const ushort* __restrict__ A, const ushort* __restrict__ Bt,
    const float* __restrict__ bias, void* __restrict__ C,
    int M, int Nn, int K, int ldc)
{
    constexpr int NB = BN / 32;                 // b-frags per wave
    __shared__ ushort As[128 * 36];
    __shared__ ushort Bs[BN * 36];
    const int t = threadIdx.x;
    const int m0 = blockIdx.x * 128, n0 = blockIdx.y * BN;
    const int l = t & 63, w = t >> 6;
    const int wr = (w >> 1) * 64, wc = (w & 1) * (BN / 2);
    const int l15 = l & 15, g8 = (l >> 4) * 8;

    // staging maps (each thread: A 2x bf16x8; B 2x (BN=128) or 1x (BN=64))
    const int ar = t >> 1, ac = (t & 1) * 16;
    const int br = (BN == 128) ? (t >> 1) : (t >> 2);
    const int bc = (BN == 128) ? ((t & 1) * 16) : ((t & 3) * 8);

    f32x4 acc[4][NB];
    #pragma unroll
    for (int i = 0; i < 4; i++)
        #pragma unroll
        for (int j = 0; j < NB; j++)
            acc[i][j] = (f32x4){0.f, 0.f, 0.f, 0.f};

    const ushort* ap = A + (size_t)(m0 + ar) * K + ac;
    const ushort* bp = Bt + (size_t)(n0 + br) * K + bc;
    bf16x8 ra0 = *(const bf16x8*)ap;
    bf16x8 ra1 = *(const bf16x8*)(ap + 8);
    bf16x8 rb0 = *(const bf16x8*)bp;
    bf16x8 rb1;
    if constexpr (BN == 128) rb1 = *(const bf16x8*)(bp + 8);

    for (int kt = 0; kt < K; kt += 32) {
        *(bf16x8*)&As[ar * 36 + ac] = ra0;
        *(bf16x8*)&As[ar * 36 + ac + 8] = ra1;
        *(bf16x8*)&Bs[br * 36 + bc] = rb0;
        if constexpr (BN == 128) *(bf16x8*)&Bs[br * 36 + bc + 8] = rb1;
        __syncthreads();
        if (kt + 32 < K) {                       // register prefetch of next tile
            ra0 = *(const bf16x8*)(ap + kt + 32);
            ra1 = *(const bf16x8*)(ap + kt + 40);
            rb0 = *(const bf16x8*)(bp + kt + 32);
            if constexpr (BN == 128) rb1 = *(const bf16x8*)(bp + kt + 40);
        }
        bf16x8 af[4], bfr[NB];
        #pragma unroll
        for (int i = 0; i < 4; i++)
            af[i] = *(bf16x8*)&As[(wr + i * 16 + l15) * 36 + g8];
        #pragma unroll
        for (int j = 0; j < NB; j++)
            bfr[j] = *(bf16x8*)&Bs[(wc + j * 16 + l15) * 36 + g8];
        #pragma unroll
        for (int i = 0; i < 4; i++)
            #pragma unroll
            for (int j = 0; j < NB; j++)
                acc[i][j] = __builtin_amdgcn_mfma_f32_16x16x32_bf16(af[i], bfr[j], acc[i][j], 0, 0, 0);
        __syncthreads();
    }
    // D mapping: col = lane&15, row = (lane>>4)*4 + r
    const int rb_ = (l >> 4) * 4;
    #pragma unroll
    for (int j = 0; j < NB; j++) {
        int cn = n0 + wc + j * 16 + l15;
        float bv = bias[cn];
        #pragma unroll
        for (int i = 0; i < 4; i++) {
            #pragma unroll
            for (int r = 0; r < 4; r++) {
                int row = m0 + wr + i * 16 + rb_ + r;
                float v = acc[i][j][r] + bv;
                if (EPI == 0) {
                    ((float*)C)[(size_t)row * ldc + cn] = v;
                } else {
                    if (EPI == 1) v = 0.5f * v * (1.f + erff(v * 0.70710678118654752f));
                    ((ushort*)C)[(size_t)row * ldc + cn] = f2b(v);
                }
            }
        }
    }
}

// ---------------------------------------------------------------------------
// MFMA flash attention (unchanged from round 7).
__global__ __launch_bounds__(256, 2) void attn_mfma(
    const ushort* __restrict__ Qm, const ushort* __restrict__ Km,
    const ushort* __restrict__ Vm, const float* __restrict__ bias,
    ushort* __restrict__ ctxb)
{
    __shared__ ushort Vt[32 * LDK];            // V^T tile: [d][k], 64 keys
    __shared__ ushort Pl[4][32 * LDK];         // per-wave P: [q][k] bf16
    const int t = threadIdx.x;
    const int bid = blockIdx.x;                // 512 = b(3)|h(3)|qt(3)
    const int qt = bid & 7;
    const int h  = (bid >> 3) & 7;
    const int b  = bid >> 6;
    const int wv = t >> 6, l = t & 63;
    const int g = l >> 4, l15 = l & 15;
    const float scale = 0.17677669529663687f;

    const int q0 = qt * 128 + wv * 32;
    const size_t base = (size_t)(b * S_) * E_ + h * D_;

    bf16x8 qf[2];
    #pragma unroll
    for (int qs = 0; qs < 2; qs++)
        qf[qs] = *(const bf16x8*)&Qm[base + (size_t)(q0 + qs * 16 + l15) * E_ + g * 8];

    f32x4 ctx[2][2] = {};
    float mrun[2] = {-3e38f, -3e38f}, lrun[2] = {0.f, 0.f};

    const int pr = t >> 3, dq = (t & 7) * 4;
    const ushort* vrow0 = &Vm[base + (size_t)(2 * pr) * E_ + dq];
    const float* bp = bias + ((size_t)b * S_ + q0) * S_;
    ushort* pw = &Pl[wv][0];

    for (int kt = 0; kt < S_; kt += 64) {
        ushort4 v0 = *(const ushort4*)&vrow0[(size_t)kt * E_];
        ushort4 v1 = *(const ushort4*)&vrow0[(size_t)kt * E_ + E_];

        f32x4 s[4][2];
        #pragma unroll
        for (int ks = 0; ks < 4; ks++) {
            bf16x8 kf = *(const bf16x8*)&Km[base + (size_t)(kt + ks * 16 + l15) * E_ + g * 8];
            #pragma unroll
            for (int qs = 0; qs < 2; qs++) {
                f32x4 z = {0.f, 0.f, 0.f, 0.f};
                s[ks][qs] = __builtin_amdgcn_mfma_f32_16x16x32_bf16(kf, qf[qs], z, 0, 0, 0);
            }
        }
        #pragma unroll
        for (int qs = 0; qs < 2; qs++) {
            const float* bq_ = bp + (size_t)(qs * 16 + l15) * S_ + kt + g * 4;
            #pragma unroll
            for (int ks = 0; ks < 4; ks++) {
                float4 bb = *(const float4*)&bq_[ks * 16];
                s[ks][qs][0] = fmaf(s[ks][qs][0], scale, bb.x);
                s[ks][qs][1] = fmaf(s[ks][qs][1], scale, bb.y);
                s[ks][qs][2] = fmaf(s[ks][qs][2], scale, bb.z);
                s[ks][qs][3] = fmaf(s[ks][qs][3], scale, bb.w);
            }
        }
        #pragma unroll
        for (int qs = 0; qs < 2; qs++) {
            float mx = s[0][qs][0];
            #pragma unroll
            for (int ks = 0; ks < 4; ks++)
                #pragma unroll
                for (int r = 0; r < 4; r++) mx = fmaxf(mx, s[ks][qs][r]);
            mx = fmaxf(mx, __shfl_xor(mx, 16, 64));
            mx = fmaxf(mx, __shfl_xor(mx, 32, 64));
            float mn = fmaxf(mrun[qs], mx);
            float corr = __expf(mrun[qs] - mn);
            mrun[qs] = mn;
            float ps = 0.f;
            #pragma unroll
            for (int ks = 0; ks < 4; ks++)
                #pragma unroll
                for (int r = 0; r < 4; r++) {
                    float e = __expf(s[ks][qs][r] - mn);
                    s[ks][qs][r] = e; ps += e;
                }
            ps += __shfl_xor(ps, 16, 64);
            ps += __shfl_xor(ps, 32, 64);
            lrun[qs] = lrun[qs] * corr + ps;
            #pragma unroll
            for (int ds = 0; ds < 2; ds++) {
                ctx[ds][qs][0] *= corr; ctx[ds][qs][1] *= corr;
                ctx[ds][qs][2] *= corr; ctx[ds][qs][3] *= corr;
            }
        }
        #pragma unroll
        for (int qs = 0; qs < 2; qs++)
            #pragma unroll
            for (int ks = 0; ks < 4; ks++) {
                uint2 pk;
                pk.x = (uint)f2b(s[ks][qs][0]) | ((uint)f2b(s[ks][qs][1]) << 16);
                pk.y = (uint)f2b(s[ks][qs][2]) | ((uint)f2b(s[ks][qs][3]) << 16);
                *(uint2*)&pw[(qs * 16 + l15) * LDK + ks * 16 + g * 4] = pk;
            }
        __syncthreads();
        {
            uint p0 = (uint)v0.x | ((uint)v1.x << 16);
            uint p1 = (uint)v0.y | ((uint)v1.y << 16);
            uint p2 = (uint)v0.z | ((uint)v1.z << 16);
            uint p3 = (uint)v0.w | ((uint)v1.w << 16);
            *(uint*)&Vt[(dq + 0) * LDK + 2 * pr] = p0;
            *(uint*)&Vt[(dq + 1) * LDK + 2 * pr] = p1;
            *(uint*)&Vt[(dq + 2) * LDK + 2 * pr] = p2;
            *(uint*)&Vt[(dq + 3) * LDK + 2 * pr] = p3;
        }
        __syncthreads();
        #pragma unroll
        for (int kc = 0; kc < 2; kc++) {
            bf16x8 pf[2], vf[2];
            #pragma unroll
            for (int qs = 0; qs < 2; qs++)
                pf[qs] = *(bf16x8*)&pw[(qs * 16 + l15) * LDK + kc * 32 + g * 8];
            #pragma unroll
            for (int ds = 0; ds < 2; ds++)
                vf[ds] = *(bf16x8*)&Vt[(ds * 16 + l15) * LDK + kc * 32 + g * 8];
            #pragma unroll
            for (int ds = 0; ds < 2; ds++)
                #pragma unroll
                for (int qs = 0; qs < 2; qs++)
                    ctx[ds][qs] = __builtin_amdgcn_mfma_f32_16x16x32_bf16(
                        vf[ds], pf[qs], ctx[ds][qs], 0, 0, 0);
        }
    }
    #pragma unroll
    for (int qs = 0; qs < 2; qs++) {
        float inv = 1.f / lrun[qs];
        ushort* op = &ctxb[base + (size_t)(q0 + qs * 16 + l15) * E_];
        #pragma unroll
        for (int ds = 0; ds < 2; ds++)
            #pragma unroll
            for (int r = 0; r < 4; r++)
                op[ds * 16 + g * 4 + r] = f2b(ctx[ds][qs][r] * inv);
    }
}

// ---------------------------------------------------------------------------
// xout = LN(xin + add) * g + b  (also emits bf16 copy)
__global__ __launch_bounds__(64) void ln_kernel(
    const float* __restrict__ xin, const float* __restrict__ add,
    const float* __restrict__ g, const float* __restrict__ bt,
    float* __restrict__ xout, ushort* __restrict__ xbout)
{
    int row = blockIdx.x, t = threadIdx.x;
    float4 xv = *(const float4*)&xin[(size_t)row * E_ + t * 4];
    float4 av = *(const float4*)&add[(size_t)row * E_ + t * 4];
    xv.x += av.x; xv.y += av.y; xv.z += av.z; xv.w += av.w;
    float sum = xv.x + xv.y + xv.z + xv.w;
    #pragma unroll
    for (int off = 32; off; off >>= 1) sum += __shfl_xor(sum, off, 64);
    float mean = sum * (1.f / 256.f);
    float dx = xv.x - mean, dy = xv.y - mean, dz = xv.z - mean, dw = xv.w - mean;
    float sq = dx * dx + dy * dy + dz * dz + dw * dw;
    #pragma unroll
    for (int off = 32; off; off >>= 1) sq += __shfl_xor(sq, off, 64);
    float rstd = rsqrtf(sq * (1.f / 256.f) + 1e-12f);
    float4 gv = *(const float4*)&g[t * 4];
    float4 bv = *(const float4*)&bt[t * 4];
    float4 ov;
    ov.x = dx * rstd * gv.x + bv.x;
    ov.y = dy * rstd * gv.y + bv.y;
    ov.z = dz * rstd * gv.z + bv.z;
    ov.w = dw * rstd * gv.w + bv.w;
    *(float4*)&xout[(size_t)row * E_ + t * 4] = ov;
    ushort4 hb;
    hb.x = f2b(ov.x); hb.y = f2b(ov.y); hb.z = f2b(ov.z); hb.w = f2b(ov.w);
    *(ushort4*)&xbout[(size_t)row * E_ + t * 4] = hb;
}

// ---------------------------------------------------------------------------
extern "C" void kernel_launch(void* const* d_in, const int* in_sizes, int n_in,
                              void* d_out, int out_size, void* d_ws, size_t ws_size,
                              hipStream_t stream) {
    const float* node_feat = (const float*)d_in[0];
    const int*   node_opc  = (const int*)d_in[1];
    const int*   dist_mat  = (const int*)d_in[2];
    const float* W_op      = (const float*)d_in[3];
    const float* W_feat    = (const float*)d_in[4];
    const float* b_feat    = (const float*)d_in[5];
    const float* W_mlp1    = (const float*)d_in[6];
    const float* b_mlp1    = (const float*)d_in[7];
    const float* W_mlp2    = (const float*)d_in[8];
    const float* b_mlp2    = (const float*)d_in[9];
    const float* cls       = (const float*)d_in[10];
    const float* dist_tab  = (const float*)d_in[11];
    const float* Wq = (const float*)d_in[12]; const float* bq = (const float*)d_in[13];
    const float* Wk = (const float*)d_in[14]; const float* bk = (const float*)d_in[15];
    const float* Wv = (const float*)d_in[16]; const float* bv = (const float*)d_in[17];
    const float* Wo = (const float*)d_in[18]; const float* bo = (const float*)d_in[19];
    const float* ln1g = (const float*)d_in[20]; const float* ln1b = (const float*)d_in[21];
    const float* Wf1 = (const float*)d_in[22]; const float* bf1 = (const float*)d_in[23];
    const float* Wf2 = (const float*)d_in[24]; const float* bf2 = (const float*)d_in[25];
    const float* ln2g = (const float*)d_in[26]; const float* ln2b = (const float*)d_in[27];

    float* out = (float*)d_out;
    float* ws  = (float*)d_ws;
    // workspace layout, float units
    float* biasb = ws;                        // 8388608
    float* x     = biasb + 8388608;           // 2097152
    float* qb    = x  + 2097152;              // 2097152
    float* kb    = qb + 2097152;              // 2097152
    float* vb    = kb + 2097152;              // 2097152 (pre-layer: h2 fp32)
    float* big   = vb + 2097152;              // 8388608 floats = 32 MB
    float* mlbuf = big + 8388608;             // 524288 (spare)
    ushort* xb   = (ushort*)(mlbuf + 524288); // 2097152 ushort
    ushort* cbb  = xb + 2097152;              // 2097152 ushort
    ushort* wts  = cbb + 2097152;             // layer + pre-layer weights
    ushort* qbb = (ushort*)qb;
    ushort* kbb = (ushort*)kb;
    ushort* vbb = (ushort*)vb;
    float*  h2f = vb;                         // pre-layer fp32 h2
    // big region: pre-layer bf16 buffers, later ffnb
    ushort* nfb   = (ushort*)big;             // 8192*160
    ushort* hcatb = nfb + 1310720;            // 8192*512
    ushort* h1b   = hcatb + 4194304;          // 8192*256
    ushort* ffnb  = (ushort*)big;             // layers: 8192*1024

    // bf16 transposed weights
    ushort* wqt  = wts;                 // 6*256*256
    ushort* wkt  = wqt + 393216;
    ushort* wvt  = wkt + 393216;
    ushort* wot  = wvt + 393216;
    ushort* wf1t = wot + 393216;        // 6*1024*256
    ushort* wf2t = wf1t + 1572864;      // 6*256*1024
    ushort* wft  = wf2t + 1572864;      // 256*160 (K=140 padded)
    ushort* wm1t = wft + 40960;         // 256*512
    ushort* wm2t = wm1t + 131072;       // 256*256

    wconv_t<<<1536, 256, 0, stream>>>(Wq, wqt, 256, 256, 256);
    wconv_t<<<1536, 256, 0, stream>>>(Wk, wkt, 256, 256, 256);
    wconv_t<<<1536, 256, 0, stream>>>(Wv, wvt, 256, 256, 256);
    wconv_t<<<1536, 256, 0, stream>>>(Wo, wot, 256, 256, 256);
    wconv_t<<<6144, 256, 0, stream>>>(Wf1, wf1t, 256, 256, 1024);
    wconv_t<<<6144, 256, 0, stream>>>(Wf2, wf2t, 1024, 1024, 256);
    wconv_t<<<160,  256, 0, stream>>>(W_feat, wft, 140, 160, 256);
    wconv_t<<<512,  256, 0, stream>>>(W_mlp1, wm1t, 512, 512, 256);
    wconv_t<<<256,  256, 0, stream>>>(W_mlp2, wm2t, 256, 256, 256);

    bias_kernel<<<32768, 256, 0, stream>>>(dist_mat, dist_tab, biasb);
    nfconv<<<5120, 256, 0, stream>>>(node_feat, nfb);
    opgather_kernel<<<8192, 256, 0, stream>>>(node_opc, W_op, hcatb);
    mgemm2<2, 64><<<dim3(64, 4), 256, 0, stream>>>(nfb, wft, b_feat,
                                                   (void*)(hcatb + 256), 8192, 256, 160, 512);
    mgemm2<1, 64><<<dim3(64, 4), 256, 0, stream>>>(hcatb, wm1t, b_mlp1,
                                                   h1b, 8192, 256, 512, 256);
    mgemm2<0, 64><<<dim3(64, 4), 256, 0, stream>>>(h1b, wm2t, b_mlp2,
                                                   h2f, 8192, 256, 256, 256);
    assemble_kernel<<<8192, 256, 0, stream>>>(cls, h2f, x, xb);

    for (int l = 0; l < L_; l++) {
        const ushort* wqt_l = wqt + l * 65536;  const float* bq_l = bq + l * 256;
        const ushort* wkt_l = wkt + l * 65536;  const float* bk_l = bk + l * 256;
        const ushort* wvt_l = wvt + l * 65536;  const float* bv_l = bv + l * 256;
        const ushort* wot_l = wot + l * 65536;  const float* bo_l = bo + l * 256;
        const ushort* wf1t_l = wf1t + l * 262144; const float* bf1_l = bf1 + l * 1024;
        const ushort* wf2t_l = wf2t + l * 262144; const float* bf2_l = bf2 + l * 256;

        mgemm2<2, 64><<<dim3(64, 4), 256, 0, stream>>>(xb, wqt_l, bq_l, qbb, 8192, 256, 256, 256);
        mgemm2<2, 64><<<dim3(64, 4), 256, 0, stream>>>(xb, wkt_l, bk_l, kbb, 8192, 256, 256, 256);
        mgemm2<2, 64><<<dim3(64, 4), 256, 0, stream>>>(xb, wvt_l, bv_l, vbb, 8192, 256, 256, 256);
        attn_mfma<<<512, 256, 0, stream>>>(qbb, kbb, vbb, biasb, cbb);
        mgemm2<0, 64><<<dim3(64, 4), 256, 0, stream>>>(cbb, wot_l, bo_l, qb, 8192, 256, 256, 256);
        ln_kernel<<<8192, 64, 0, stream>>>(x, qb, ln1g + l * 256, ln1b + l * 256, x, xb);
        mgemm2<1, 128><<<dim3(64, 8), 256, 0, stream>>>(xb, wf1t_l, bf1_l, ffnb, 8192, 1024, 256, 1024);
        mgemm2<0, 64><<<dim3(64, 4), 256, 0, stream>>>((const ushort*)ffnb, wf2t_l, bf2_l, qb,
                                                       8192, 256, 1024, 256);
        ln_kernel<<<8192, 64, 0, stream>>>(x, qb, ln2g + l * 256, ln2b + l * 256,
                                           (l == L_ - 1) ? out : x, xb);
    }
}

// Round 12
// 850.660 us; speedup vs baseline: 5.8553x; 1.1159x over previous
//
#include <hip/hip_runtime.h>
#include <math.h>

#define B_ 8
#define N_ 1023
#define S_ 1024
#define E_ 256
#define H_ 8
#define D_ 32
#define L_ 6
#define F_ 1024
#define LDK 72   // attn LDS leading dim (k) for Vt/P tiles

typedef __attribute__((ext_vector_type(8))) short bf16x8;
typedef __attribute__((ext_vector_type(4))) float f32x4;

__device__ __forceinline__ ushort f2b(float x) {
    unsigned u = __float_as_uint(x);
    return (ushort)((u + 0x7fffu + ((u >> 16) & 1u)) >> 16);
}
// packed f32x2 -> bf16x2 (RNE), src0 -> low16
__device__ __forceinline__ uint cvtpk(float lo, float hi) {
    uint r;
    asm("v_cvt_pk_bf16_f32 %0, %1, %2" : "=v"(r) : "v"(lo), "v"(hi));
    return r;
}

// ---------------------------------------------------------------------------
__global__ __launch_bounds__(256) void bias_kernel(const int* __restrict__ dm,
                                                   const float* __restrict__ table,
                                                   float* __restrict__ out) {
    int idx = blockIdx.x * 256 + threadIdx.x;          // exactly B_*S_*S_
    int d = dm[idx];
    int ii = ((unsigned)d > 30u) ? 31 : d;
    out[idx] = table[ii];
}

// node_feat -> bf16, zero-padded to [8192][160]
__global__ __launch_bounds__(256) void nfconv(const float* __restrict__ nf,
                                              ushort* __restrict__ out) {
    int idx = blockIdx.x * 256 + threadIdx.x;          // 8192*160
    int r = idx / 160, k = idx - r * 160;
    float v = (r < 8184 && k < 140) ? nf[r * 140 + k] : 0.f;
    out[idx] = f2b(v);
}

// op embedding gather (bf16) into left half of hcatb (ld 512); rows>=8184 zero
__global__ __launch_bounds__(256) void opgather_kernel(const int* __restrict__ opc,
                                                       const float* __restrict__ W_op,
                                                       ushort* __restrict__ hcatb) {
    int idx = blockIdx.x * 256 + threadIdx.x;          // 8192*256
    int row = idx >> 8, c = idx & 255;
    float v = (row < 8184) ? W_op[opc[row] * 256 + c] : 0.f;
    hcatb[(size_t)row * 512 + c] = f2b(v);
}

// x[b,0,:]=cls ; x[b,1+n,:]=h[b*N+n,:]   (also emits bf16 copy)
__global__ __launch_bounds__(256) void assemble_kernel(const float* __restrict__ cls,
                                                       const float* __restrict__ h,
                                                       float* __restrict__ x,
                                                       ushort* __restrict__ xb) {
    int idx = blockIdx.x * 256 + threadIdx.x;          // B_*S_*E_
    int c = idx & 255;
    int s = (idx >> 8) & 1023;
    int b = idx >> 18;
    float v = (s == 0) ? cls[c] : h[((size_t)(b * N_ + s - 1)) * 256 + c];
    x[idx] = v;
    xb[idx] = f2b(v);
}

// ---------------------------------------------------------------------------
// Weight convert + transpose + K-pad: out[l][n][kp] = kp<K ? bf16(in[l][kp][n]) : 0
__global__ __launch_bounds__(256) void wconv_t(const float* __restrict__ in,
                                               ushort* __restrict__ out,
                                               int K, int Kp, int Nn) {
    int idx = blockIdx.x * 256 + threadIdx.x;
    int per = Kp * Nn;
    int lw = idx / per, rem = idx - lw * per;
    int n = rem / Kp, k = rem - n * Kp;
    out[idx] = (k < K) ? f2b(in[(size_t)lw * K * Nn + (size_t)k * Nn + n]) : (ushort)0;
}

// QKV concat: out[l][n][k], n in 0..767 = (Wq|Wk|Wv) col n%256, transposed
__global__ __launch_bounds__(256) void wconv_qkv(const float* __restrict__ Wq,
                                                 const float* __restrict__ Wk,
                                                 const float* __restrict__ Wv,
                                                 ushort* __restrict__ out) {
    int idx = blockIdx.x * 256 + threadIdx.x;          // 6*768*256
    int l = idx / 196608, rem = idx - l * 196608;
    int n = rem >> 8, k = rem & 255;
    const float* src = (n < 256) ? Wq : (n < 512) ? Wk : Wv;
    out[idx] = f2b(src[(size_t)l * 65536 + k * 256 + (n & 255)]);
}

__global__ __launch_bounds__(256) void bcat_qkv(const float* __restrict__ bq,
                                                const float* __restrict__ bk,
                                                const float* __restrict__ bv,
                                                float* __restrict__ out) {
    int idx = blockIdx.x * 256 + threadIdx.x;          // 18*256 = 4608 exact
    int l = idx / 768, n = idx - l * 768;
    out[idx] = (n < 256) ? bq[l * 256 + n]
             : (n < 512) ? bk[l * 256 + n - 256]
                         : bv[l * 256 + n - 512];
}

// ---------------------------------------------------------------------------
// MFMA bf16 GEMM: C[M,N] = epi(A[M,K]_bf16 @ B[K,N] + bias[N]); Bt[N][K].
// BM=BN=64, BK=32, 256 thr = 4 waves (2x2); wave 32x32 via 2x2 16x16x32 frags.
// LDS pitch 36 ushort (72B): rows land on distinct bank groups (<=2-way).
// Grid-maximized: these GEMMs are occupancy-bound, not density-bound.
// EPI 0: fp32 out. EPI 1: exact GELU, bf16 out. EPI 2: plain bf16 out.
template<int EPI>
__global__ __launch_bounds__(256) void mgemm2(
    const ushort* __restrict__ A, const ushort* __restrict__ Bt,
    const float* __restrict__ bias, void* __restrict__ C,
    int K, int ldc)
{
    __shared__ ushort As[64 * 36];
    __shared__ ushort Bs[64 * 36];
    const int t = threadIdx.x;
    const int m0 = blockIdx.x * 64, n0 = blockIdx.y * 64;
    const int l = t & 63, w = t >> 6;
    const int wr = (w >> 1) * 32, wc = (w & 1) * 32;
    const int l15 = l & 15, g8 = (l >> 4) * 8;
    const int sr = t >> 2, sc = (t & 3) * 8;

    f32x4 acc00 = {0.f,0.f,0.f,0.f}, acc01 = acc00, acc10 = acc00, acc11 = acc00;

    const ushort* ap = A + (size_t)(m0 + sr) * K + sc;
    const ushort* bp = Bt + (size_t)(n0 + sr) * K + sc;
    bf16x8 ra = *(const bf16x8*)ap;
    bf16x8 rb = *(const bf16x8*)bp;

    for (int kt = 0; kt < K; kt += 32) {
        *(bf16x8*)&As[sr * 36 + sc] = ra;
        *(bf16x8*)&Bs[sr * 36 + sc] = rb;
        __syncthreads();
        if (kt + 32 < K) {                       // register prefetch of next tile
            ra = *(const bf16x8*)(ap + kt + 32);
            rb = *(const bf16x8*)(bp + kt + 32);
        }
        bf16x8 a0 = *(bf16x8*)&As[(wr + l15) * 36 + g8];
        bf16x8 a1 = *(bf16x8*)&As[(wr + 16 + l15) * 36 + g8];
        bf16x8 b0 = *(bf16x8*)&Bs[(wc + l15) * 36 + g8];
        bf16x8 b1 = *(bf16x8*)&Bs[(wc + 16 + l15) * 36 + g8];
        acc00 = __builtin_amdgcn_mfma_f32_16x16x32_bf16(a0, b0, acc00, 0, 0, 0);
        acc01 = __builtin_amdgcn_mfma_f32_16x16x32_bf16(a0, b1, acc01, 0, 0, 0);
        acc10 = __builtin_amdgcn_mfma_f32_16x16x32_bf16(a1, b0, acc10, 0, 0, 0);
        acc11 = __builtin_amdgcn_mfma_f32_16x16x32_bf16(a1, b1, acc11, 0, 0, 0);
        __syncthreads();
    }
    // D mapping: col = lane&15, row = (lane>>4)*4 + r
    const int cn = n0 + wc + l15;
    const int rbase = m0 + wr + (l >> 4) * 4;
    float bv0 = bias[cn], bv1 = bias[cn + 16];
    #pragma unroll
    for (int i = 0; i < 2; i++) {
        f32x4 aj0 = i ? acc10 : acc00;
        f32x4 aj1 = i ? acc11 : acc01;
        #pragma unroll
        for (int r = 0; r < 4; r++) {
            int row = rbase + i * 16 + r;
            float v0 = aj0[r] + bv0;
            float v1 = aj1[r] + bv1;
            if (EPI == 0) {
                ((float*)C)[(size_t)row * ldc + cn] = v0;
                ((float*)C)[(size_t)row * ldc + cn + 16] = v1;
            } else {
                if (EPI == 1) {
                    v0 = 0.5f * v0 * (1.f + erff(v0 * 0.70710678118654752f));
                    v1 = 0.5f * v1 * (1.f + erff(v1 * 0.70710678118654752f));
                }
                ((ushort*)C)[(size_t)row * ldc + cn] = f2b(v0);
                ((ushort*)C)[(size_t)row * ldc + cn + 16] = f2b(v1);
            }
        }
    }
}

// ---------------------------------------------------------------------------
// MFMA flash attention; Q/K/V read from fused qkv buffer with row stride ldq.
__global__ __launch_bounds__(256, 2) void attn_mfma(
    const ushort* __restrict__ Qm, const ushort* __restrict__ Km,
    const ushort* __restrict__ Vm, const float* __restrict__ bias,
    ushort* __restrict__ ctxb, int ldq)
{
    __shared__ ushort Vt[32 * LDK];            // V^T tile: [d][k], 64 keys
    __shared__ ushort Pl[4][32 * LDK];         // per-wave P: [q][k] bf16
    const int t = threadIdx.x;
    const int bid = blockIdx.x;                // 512 = b(3)|h(3)|qt(3)
    const int qt = bid & 7;
    const int h  = (bid >> 3) & 7;
    const int b  = bid >> 6;
    const int wv = t >> 6, l = t & 63;
    const int g = l >> 4, l15 = l & 15;
    const float scale = 0.17677669529663687f;

    const int q0 = qt * 128 + wv * 32;
    const size_t base  = (size_t)(b * S_) * ldq + h * D_;
    const size_t cbase = (size_t)(b * S_) * E_  + h * D_;

    bf16x8 qf[2];
    #pragma unroll
    for (int qs = 0; qs < 2; qs++)
        qf[qs] = *(const bf16x8*)&Qm[base + (size_t)(q0 + qs * 16 + l15) * ldq + g * 8];

    f32x4 ctx[2][2] = {};
    float mrun[2] = {-3e38f, -3e38f}, lrun[2] = {0.f, 0.f};

    const int pr = t >> 3, dq = (t & 7) * 4;
    const ushort* vrow0 = &Vm[base + (size_t)(2 * pr) * ldq + dq];
    const float* bp = bias + ((size_t)b * S_ + q0) * S_;
    ushort* pw = &Pl[wv][0];

    for (int kt = 0; kt < S_; kt += 64) {
        ushort4 v0 = *(const ushort4*)&vrow0[(size_t)kt * ldq];
        ushort4 v1 = *(const ushort4*)&vrow0[(size_t)kt * ldq + ldq];

        f32x4 s[4][2];
        #pragma unroll
        for (int ks = 0; ks < 4; ks++) {
            bf16x8 kf = *(const bf16x8*)&Km[base + (size_t)(kt + ks * 16 + l15) * ldq + g * 8];
            #pragma unroll
            for (int qs = 0; qs < 2; qs++) {
                f32x4 z = {0.f, 0.f, 0.f, 0.f};
                s[ks][qs] = __builtin_amdgcn_mfma_f32_16x16x32_bf16(kf, qf[qs], z, 0, 0, 0);
            }
        }
        #pragma unroll
        for (int qs = 0; qs < 2; qs++) {
            const float* bq_ = bp + (size_t)(qs * 16 + l15) * S_ + kt + g * 4;
            #pragma unroll
            for (int ks = 0; ks < 4; ks++) {
                float4 bb = *(const float4*)&bq_[ks * 16];
                s[ks][qs][0] = fmaf(s[ks][qs][0], scale, bb.x);
                s[ks][qs][1] = fmaf(s[ks][qs][1], scale, bb.y);
                s[ks][qs][2] = fmaf(s[ks][qs][2], scale, bb.z);
                s[ks][qs][3] = fmaf(s[ks][qs][3], scale, bb.w);
            }
        }
        #pragma unroll
        for (int qs = 0; qs < 2; qs++) {
            float mx = s[0][qs][0];
            #pragma unroll
            for (int ks = 0; ks < 4; ks++)
                #pragma unroll
                for (int r = 0; r < 4; r++) mx = fmaxf(mx, s[ks][qs][r]);
            mx = fmaxf(mx, __shfl_xor(mx, 16, 64));
            mx = fmaxf(mx, __shfl_xor(mx, 32, 64));
            float mn = fmaxf(mrun[qs], mx);
            float corr = __expf(mrun[qs] - mn);
            mrun[qs] = mn;
            float ps = 0.f;
            #pragma unroll
            for (int ks = 0; ks < 4; ks++)
                #pragma unroll
                for (int r = 0; r < 4; r++) {
                    float e = __expf(s[ks][qs][r] - mn);
                    s[ks][qs][r] = e; ps += e;
                }
            ps += __shfl_xor(ps, 16, 64);
            ps += __shfl_xor(ps, 32, 64);
            lrun[qs] = lrun[qs] * corr + ps;
            #pragma unroll
            for (int ds = 0; ds < 2; ds++) {
                ctx[ds][qs][0] *= corr; ctx[ds][qs][1] *= corr;
                ctx[ds][qs][2] *= corr; ctx[ds][qs][3] *= corr;
            }
        }
        // P -> LDS [q][k] bf16 via packed cvt (1 op / 2 elems)
        #pragma unroll
        for (int qs = 0; qs < 2; qs++)
            #pragma unroll
            for (int ks = 0; ks < 4; ks++) {
                uint2 pk;
                pk.x = cvtpk(s[ks][qs][0], s[ks][qs][1]);
                pk.y = cvtpk(s[ks][qs][2], s[ks][qs][3]);
                *(uint2*)&pw[(qs * 16 + l15) * LDK + ks * 16 + g * 4] = pk;
            }
        __syncthreads();
        {
            uint p0 = (uint)v0.x | ((uint)v1.x << 16);
            uint p1 = (uint)v0.y | ((uint)v1.y << 16);
            uint p2 = (uint)v0.z | ((uint)v1.z << 16);
            uint p3 = (uint)v0.w | ((uint)v1.w << 16);
            *(uint*)&Vt[(dq + 0) * LDK + 2 * pr] = p0;
            *(uint*)&Vt[(dq + 1) * LDK + 2 * pr] = p1;
            *(uint*)&Vt[(dq + 2) * LDK + 2 * pr] = p2;
            *(uint*)&Vt[(dq + 3) * LDK + 2 * pr] = p3;
        }
        __syncthreads();
        #pragma unroll
        for (int kc = 0; kc < 2; kc++) {
            bf16x8 pf[2], vf[2];
            #pragma unroll
            for (int qs = 0; qs < 2; qs++)
                pf[qs] = *(bf16x8*)&pw[(qs * 16 + l15) * LDK + kc * 32 + g * 8];
            #pragma unroll
            for (int ds = 0; ds < 2; ds++)
                vf[ds] = *(bf16x8*)&Vt[(ds * 16 + l15) * LDK + kc * 32 + g * 8];
            #pragma unroll
            for (int ds = 0; ds < 2; ds++)
                #pragma unroll
                for (int qs = 0; qs < 2; qs++)
                    ctx[ds][qs] = __builtin_amdgcn_mfma_f32_16x16x32_bf16(
                        vf[ds], pf[qs], ctx[ds][qs], 0, 0, 0);
        }
    }
    #pragma unroll
    for (int qs = 0; qs < 2; qs++) {
        float inv = 1.f / lrun[qs];
        ushort* op = &ctxb[cbase + (size_t)(q0 + qs * 16 + l15) * E_];
        #pragma unroll
        for (int ds = 0; ds < 2; ds++) {
            uint2 pkv;
            pkv.x = cvtpk(ctx[ds][qs][0] * inv, ctx[ds][qs][1] * inv);
            pkv.y = cvtpk(ctx[ds][qs][2] * inv, ctx[ds][qs][3] * inv);
            *(uint2*)&op[ds * 16 + g * 4] = pkv;
        }
    }
}

// ---------------------------------------------------------------------------
// xout = LN(xin + add) * g + b  (also emits bf16 copy)
__global__ __launch_bounds__(64) void ln_kernel(
    const float* __restrict__ xin, const float* __restrict__ add,
    const float* __restrict__ g, const float* __restrict__ bt,
    float* __restrict__ xout, ushort* __restrict__ xbout)
{
    int row = blockIdx.x, t = threadIdx.x;
    float4 xv = *(const float4*)&xin[(size_t)row * E_ + t * 4];
    float4 av = *(const float4*)&add[(size_t)row * E_ + t * 4];
    xv.x += av.x; xv.y += av.y; xv.z += av.z; xv.w += av.w;
    float sum = xv.x + xv.y + xv.z + xv.w;
    #pragma unroll
    for (int off = 32; off; off >>= 1) sum += __shfl_xor(sum, off, 64);
    float mean = sum * (1.f / 256.f);
    float dx = xv.x - mean, dy = xv.y - mean, dz = xv.z - mean, dw = xv.w - mean;
    float sq = dx * dx + dy * dy + dz * dz + dw * dw;
    #pragma unroll
    for (int off = 32; off; off >>= 1) sq += __shfl_xor(sq, off, 64);
    float rstd = rsqrtf(sq * (1.f / 256.f) + 1e-12f);
    float4 gv = *(const float4*)&g[t * 4];
    float4 bv = *(const float4*)&bt[t * 4];
    float4 ov;
    ov.x = dx * rstd * gv.x + bv.x;
    ov.y = dy * rstd * gv.y + bv.y;
    ov.z = dz * rstd * gv.z + bv.z;
    ov.w = dw * rstd * gv.w + bv.w;
    *(float4*)&xout[(size_t)row * E_ + t * 4] = ov;
    uint2 hb;
    hb.x = cvtpk(ov.x, ov.y);
    hb.y = cvtpk(ov.z, ov.w);
    *(uint2*)&xbout[(size_t)row * E_ + t * 4] = hb;
}

// ---------------------------------------------------------------------------
extern "C" void kernel_launch(void* const* d_in, const int* in_sizes, int n_in,
                              void* d_out, int out_size, void* d_ws, size_t ws_size,
                              hipStream_t stream) {
    const float* node_feat = (const float*)d_in[0];
    const int*   node_opc  = (const int*)d_in[1];
    const int*   dist_mat  = (const int*)d_in[2];
    const float* W_op      = (const float*)d_in[3];
    const float* W_feat    = (const float*)d_in[4];
    const float* b_feat    = (const float*)d_in[5];
    const float* W_mlp1    = (const float*)d_in[6];
    const float* b_mlp1    = (const float*)d_in[7];
    const float* W_mlp2    = (const float*)d_in[8];
    const float* b_mlp2    = (const float*)d_in[9];
    const float* cls       = (const float*)d_in[10];
    const float* dist_tab  = (const float*)d_in[11];
    const float* Wq = (const float*)d_in[12]; const float* bq = (const float*)d_in[13];
    const float* Wk = (const float*)d_in[14]; const float* bk = (const float*)d_in[15];
    const float* Wv = (const float*)d_in[16]; const float* bv = (const float*)d_in[17];
    const float* Wo = (const float*)d_in[18]; const float* bo = (const float*)d_in[19];
    const float* ln1g = (const float*)d_in[20]; const float* ln1b = (const float*)d_in[21];
    const float* Wf1 = (const float*)d_in[22]; const float* bf1 = (const float*)d_in[23];
    const float* Wf2 = (const float*)d_in[24]; const float* bf2 = (const float*)d_in[25];
    const float* ln2g = (const float*)d_in[26]; const float* ln2b = (const float*)d_in[27];

    float* out = (float*)d_out;
    float* ws  = (float*)d_ws;
    // workspace layout, float units (~98 MB)
    float* biasb = ws;                         // 8388608
    float* x     = biasb + 8388608;            // 2097152
    float* resid = x + 2097152;                // 2097152 (Wo/FFN2 fp32; pre-layer h2f)
    float* big   = resid + 2097152;            // 4194304 floats (ffnb | pre-layer bufs)
    ushort* qkvb = (ushort*)(big + 4194304);   // 8192*768 ushort
    ushort* cbb  = qkvb + 6291456;             // 8192*256 ushort
    ushort* xb   = cbb + 2097152;              // 8192*256 ushort
    ushort* wts  = xb + 2097152;
    float*  h2f  = resid;
    ushort* nfb   = (ushort*)big;              // 8192*160
    ushort* hcatb = nfb + 1310720;             // 8192*512
    ushort* h1b   = hcatb + 4194304;           // 8192*256
    ushort* ffnb  = (ushort*)big;              // layers: 8192*1024

    // bf16 transposed weights
    ushort* wqkvt = wts;                 // 6*768*256 = 1179648
    ushort* wot   = wqkvt + 1179648;     // 6*256*256 = 393216
    ushort* wf1t  = wot + 393216;        // 6*1024*256
    ushort* wf2t  = wf1t + 1572864;      // 6*256*1024
    ushort* wft   = wf2t + 1572864;      // 256*160
    ushort* wm1t  = wft + 40960;         // 256*512
    ushort* wm2t  = wm1t + 131072;       // 256*256
    float*  bqkvb = (float*)(wm2t + 65536);  // 6*768 fp32

    wconv_qkv<<<4608, 256, 0, stream>>>(Wq, Wk, Wv, wqkvt);
    bcat_qkv<<<18, 256, 0, stream>>>(bq, bk, bv, bqkvb);
    wconv_t<<<1536, 256, 0, stream>>>(Wo, wot, 256, 256, 256);
    wconv_t<<<6144, 256, 0, stream>>>(Wf1, wf1t, 256, 256, 1024);
    wconv_t<<<6144, 256, 0, stream>>>(Wf2, wf2t, 1024, 1024, 256);
    wconv_t<<<160,  256, 0, stream>>>(W_feat, wft, 140, 160, 256);
    wconv_t<<<512,  256, 0, stream>>>(W_mlp1, wm1t, 512, 512, 256);
    wconv_t<<<256,  256, 0, stream>>>(W_mlp2, wm2t, 256, 256, 256);

    bias_kernel<<<32768, 256, 0, stream>>>(dist_mat, dist_tab, biasb);
    nfconv<<<5120, 256, 0, stream>>>(node_feat, nfb);
    opgather_kernel<<<8192, 256, 0, stream>>>(node_opc, W_op, hcatb);
    mgemm2<2><<<dim3(128, 4), 256, 0, stream>>>(nfb, wft, b_feat,
                                                (void*)(hcatb + 256), 160, 512);
    mgemm2<1><<<dim3(128, 4), 256, 0, stream>>>(hcatb, wm1t, b_mlp1, h1b, 512, 256);
    mgemm2<0><<<dim3(128, 4), 256, 0, stream>>>(h1b, wm2t, b_mlp2, h2f, 256, 256);
    assemble_kernel<<<8192, 256, 0, stream>>>(cls, h2f, x, xb);

    for (int l = 0; l < L_; l++) {
        const ushort* wqkvt_l = wqkvt + l * 196608; const float* bqkv_l = bqkvb + l * 768;
        const ushort* wot_l  = wot + l * 65536;     const float* bo_l = bo + l * 256;
        const ushort* wf1t_l = wf1t + l * 262144;   const float* bf1_l = bf1 + l * 1024;
        const ushort* wf2t_l = wf2t + l * 262144;   const float* bf2_l = bf2 + l * 256;

        mgemm2<2><<<dim3(128, 12), 256, 0, stream>>>(xb, wqkvt_l, bqkv_l, qkvb, 256, 768);
        attn_mfma<<<512, 256, 0, stream>>>(qkvb, qkvb + 256, qkvb + 512, biasb, cbb, 768);
        mgemm2<0><<<dim3(128, 4), 256, 0, stream>>>(cbb, wot_l, bo_l, resid, 256, 256);
        ln_kernel<<<8192, 64, 0, stream>>>(x, resid, ln1g + l * 256, ln1b + l * 256, x, xb);
        mgemm2<1><<<dim3(128, 16), 256, 0, stream>>>(xb, wf1t_l, bf1_l, ffnb, 256, 1024);
        mgemm2<0><<<dim3(128, 4), 256, 0, stream>>>((const ushort*)ffnb, wf2t_l, bf2_l,
                                                    resid, 1024, 256);
        ln_kernel<<<8192, 64, 0, stream>>>(x, resid, ln2g + l * 256, ln2b + l * 256,
                                           (l == L_ - 1) ? out : x, xb);
    }
}